// Round 1
// baseline (8419.094 us; speedup 1.0000x reference)
//
#include <hip/hip_runtime.h>

#define NVN 50000
#define NUN 50000

// ---------------------------------------------------------------- degrees
__global__ __launch_bounds__(256) void deg_kernel(const int* __restrict__ ev,
                                                  const int* __restrict__ eu,
                                                  float* __restrict__ dv,
                                                  float* __restrict__ du, int ne) {
  int i = blockIdx.x * 256 + threadIdx.x;
  if (i < ne) {
    unsafeAtomicAdd(&dv[ev[i]], 1.0f);
    unsafeAtomicAdd(&du[eu[i]], 1.0f);
  }
}

// ------------------------------------------------- scatter-add of 128-dim rows
// 32 threads per edge, one float4 each.
__global__ __launch_bounds__(256) void scatter_add_d128(
    const float* __restrict__ src, const int* __restrict__ gidx,
    const int* __restrict__ sidx, float* __restrict__ dst, int ne) {
  long long t = (long long)blockIdx.x * 256 + threadIdx.x;
  int e = (int)(t >> 5);
  if (e >= ne) return;
  int c = ((int)t & 31) * 4;
  const float4 v = *reinterpret_cast<const float4*>(src + (size_t)gidx[e] * 128 + c);
  float* d = dst + (size_t)sidx[e] * 128 + c;
  unsafeAtomicAdd(d + 0, v.x);
  unsafeAtomicAdd(d + 1, v.y);
  unsafeAtomicAdd(d + 2, v.z);
  unsafeAtomicAdd(d + 3, v.w);
}

// ------------------------------------------------- row scale by 1/max(deg,1)
__global__ __launch_bounds__(256) void scale_rows_d128(float* __restrict__ x,
                                                       const float* __restrict__ deg,
                                                       int n) {
  int t = blockIdx.x * 256 + threadIdx.x;
  if (t >= n * 32) return;
  int r = t >> 5, c = (t & 31) * 4;
  float inv = 1.0f / fmaxf(deg[r], 1.0f);
  float4* p = reinterpret_cast<float4*>(x + (size_t)r * 128 + c);
  float4 v = *p;
  v.x *= inv; v.y *= inv; v.z *= inv; v.w *= inv;
  *p = v;
}

// ---------------------------- out = prelu(acc/max(deg,1) + bias) (stage 2)
__global__ __launch_bounds__(256) void finalize_mean_bias_prelu(
    const float* __restrict__ acc, const float* __restrict__ deg,
    const float* __restrict__ bias, const float* __restrict__ slope,
    float* __restrict__ out, int ldo, int n) {
  int t = blockIdx.x * 256 + threadIdx.x;
  if (t >= n * 32) return;
  int r = t >> 5, c = (t & 31) * 4;
  float inv = 1.0f / fmaxf(deg[r], 1.0f);
  float s = slope[0];
  float4 v = *reinterpret_cast<const float4*>(acc + (size_t)r * 128 + c);
  float4 b = *reinterpret_cast<const float4*>(bias + c);
  v.x = v.x * inv + b.x;
  v.y = v.y * inv + b.y;
  v.z = v.z * inv + b.z;
  v.w = v.w * inv + b.w;
  v.x = v.x >= 0.f ? v.x : v.x * s;
  v.y = v.y >= 0.f ? v.y : v.y * s;
  v.z = v.z >= 0.f ? v.z : v.z * s;
  v.w = v.w >= 0.f ? v.w : v.w * s;
  *reinterpret_cast<float4*>(out + (size_t)r * ldo + c) = v;
}

// ---------------------------- out = (acc + e3) / (deg + 1) (stage 3)
__global__ __launch_bounds__(256) void finalize_s3(
    const float* __restrict__ acc, const float* __restrict__ e3,
    const float* __restrict__ deg, float* __restrict__ out, int ldo, int n) {
  int t = blockIdx.x * 256 + threadIdx.x;
  if (t >= n * 32) return;
  int r = t >> 5, c = (t & 31) * 4;
  float inv = 1.0f / (deg[r] + 1.0f);
  float4 a = *reinterpret_cast<const float4*>(acc + (size_t)r * 128 + c);
  float4 e = *reinterpret_cast<const float4*>(e3 + (size_t)r * 128 + c);
  a.x = (a.x + e.x) * inv;
  a.y = (a.y + e.y) * inv;
  a.z = (a.z + e.z) * inv;
  a.w = (a.w + e.w) * inv;
  *reinterpret_cast<float4*>(out + (size_t)r * ldo + c) = a;
}

// ---------------------------------------------------------------- f32 GEMM
// C[M,N] = act(concat(A1,A2) @ W + bias). 64x64 tile, BK=16, 256 threads,
// 4x4 micro-tile per thread. K1,K2 multiples of 16; N multiple of 64.
__global__ __launch_bounds__(256) void gemm_f32(
    const float* __restrict__ A1, int lda1, int K1,
    const float* __restrict__ A2, int lda2, int K2,
    const float* __restrict__ W, int N,
    const float* __restrict__ bias, const float* __restrict__ slope,
    float* __restrict__ C, int ldc, int M) {
  __shared__ float As[16][64];
  __shared__ float Ws[16][64];
  const int K = K1 + K2;
  const int bm = blockIdx.y * 64;
  const int bn = blockIdx.x * 64;
  const int tid = threadIdx.x;
  const int tr = tid >> 4;   // 0..15
  const int tc = tid & 15;   // 0..15

  float acc[4][4];
#pragma unroll
  for (int i = 0; i < 4; ++i)
#pragma unroll
    for (int j = 0; j < 4; ++j) acc[i][j] = 0.f;

  const int ar = tid >> 2;        // 0..63 (row in tile)
  const int ak = (tid & 3) * 4;   // 0,4,8,12
  const int wk = tid >> 4;        // 0..15
  const int wn = (tid & 15) * 4;  // 0..60

  for (int k0 = 0; k0 < K; k0 += 16) {
    float4 av = make_float4(0.f, 0.f, 0.f, 0.f);
    int row = bm + ar;
    if (row < M) {
      int kg = k0 + ak;
      if (kg < K1)
        av = *reinterpret_cast<const float4*>(A1 + (size_t)row * lda1 + kg);
      else
        av = *reinterpret_cast<const float4*>(A2 + (size_t)row * lda2 + (kg - K1));
    }
    As[ak + 0][ar] = av.x;
    As[ak + 1][ar] = av.y;
    As[ak + 2][ar] = av.z;
    As[ak + 3][ar] = av.w;
    const float4 wv =
        *reinterpret_cast<const float4*>(W + (size_t)(k0 + wk) * N + bn + wn);
    *reinterpret_cast<float4*>(&Ws[wk][wn]) = wv;
    __syncthreads();
#pragma unroll
    for (int kk = 0; kk < 16; ++kk) {
      float a[4], b[4];
#pragma unroll
      for (int i = 0; i < 4; ++i) a[i] = As[kk][tr * 4 + i];
#pragma unroll
      for (int j = 0; j < 4; ++j) b[j] = Ws[kk][tc * 4 + j];
#pragma unroll
      for (int i = 0; i < 4; ++i)
#pragma unroll
        for (int j = 0; j < 4; ++j) acc[i][j] = fmaf(a[i], b[j], acc[i][j]);
    }
    __syncthreads();
  }
  const bool has_act = (slope != nullptr);
  const float s = has_act ? slope[0] : 1.0f;
#pragma unroll
  for (int i = 0; i < 4; ++i) {
    int row = bm + tr * 4 + i;
    if (row >= M) continue;
#pragma unroll
    for (int j = 0; j < 4; ++j) {
      int col = bn + tc * 4 + j;
      float v = acc[i][j] + (bias ? bias[col] : 0.f);
      if (has_act && v < 0.f) v *= s;
      C[(size_t)row * ldc + col] = v;
    }
  }
}

extern "C" void kernel_launch(void* const* d_in, const int* in_sizes, int n_in,
                              void* d_out, int out_size, void* d_ws, size_t ws_size,
                              hipStream_t stream) {
  const float* features_v = (const float*)d_in[0];
  const float* features_u = (const float*)d_in[1];
  const int* edge_v = (const int*)d_in[2];
  const int* edge_u = (const int*)d_in[3];
  const float* Wv1 = (const float*)d_in[4];
  const float* bv1 = (const float*)d_in[5];
  const float* av1 = (const float*)d_in[6];
  const float* Wu1 = (const float*)d_in[7];
  const float* bu1 = (const float*)d_in[8];
  const float* au1 = (const float*)d_in[9];
  const float* Wv2 = (const float*)d_in[10];
  const float* bv2 = (const float*)d_in[11];
  const float* av2 = (const float*)d_in[12];
  const float* Wu2 = (const float*)d_in[13];
  const float* bu2 = (const float*)d_in[14];
  const float* au2 = (const float*)d_in[15];
  const float* Wv3 = (const float*)d_in[16];
  const float* bv3 = (const float*)d_in[17];
  const float* Wu3 = (const float*)d_in[18];
  const float* bu3 = (const float*)d_in[19];
  const int ne = in_sizes[2];

  float* ws = (float*)d_ws;
  float* dv = ws;                        // [NV]
  float* du = dv + NVN;                  // [NU]
  float* P1 = du + NUN;                  // [NV*128]
  float* P2 = P1 + (size_t)NVN * 128;    // [NU*128]
  float* P3 = P2 + (size_t)NUN * 128;    // [NV*256]
  float* P4 = P3 + (size_t)NVN * 256;    // [NU*256]

  float* out_v = (float*)d_out;                 // [NV,256]
  float* out_u = out_v + (size_t)NVN * 256;     // [NU,256]

  const int sg = (int)(((long long)ne * 32 + 255) / 256);
  const int rg = (NVN * 32 + 255) / 256;  // NV==NU
  const dim3 g1(256 / 64, (NVN + 63) / 64);
  const dim3 g2(128 / 64, (NVN + 63) / 64);

  // degrees (shared by all three stages)
  hipMemsetAsync(dv, 0, (size_t)(NVN + NUN) * 4, stream);
  deg_kernel<<<(ne + 255) / 256, 256, 0, stream>>>(edge_v, edge_u, dv, du, ne);

  // ---- stage 1: neighbor means of raw features
  hipMemsetAsync(P1, 0, (size_t)NVN * 128 * 4, stream);
  hipMemsetAsync(P2, 0, (size_t)NUN * 128 * 4, stream);
  scatter_add_d128<<<sg, 256, 0, stream>>>(features_u, edge_u, edge_v, P1, ne);
  scatter_add_d128<<<sg, 256, 0, stream>>>(features_v, edge_v, edge_u, P2, ne);
  scale_rows_d128<<<rg, 256, 0, stream>>>(P1, dv, NVN);
  scale_rows_d128<<<rg, 256, 0, stream>>>(P2, du, NUN);

  // ve1 = prelu(vneighbor @ Wv1 + bv1) -> P3 ; ue1 -> P4
  gemm_f32<<<g1, 256, 0, stream>>>(P1, 128, 128, nullptr, 0, 0, Wv1, 256, bv1, av1, P3, 256, NVN);
  gemm_f32<<<g1, 256, 0, stream>>>(P2, 128, 128, nullptr, 0, 0, Wu1, 256, bu1, au1, P4, 256, NUN);

  // ---- stage 2 (matmul pushed before the mean; both are linear):
  // t_u = ue1 @ Wv2 -> P2 ; t_v = ve1 @ Wu2 -> P1
  gemm_f32<<<g2, 256, 0, stream>>>(P4, 256, 256, nullptr, 0, 0, Wv2, 128, nullptr, nullptr, P2, 128, NUN);
  gemm_f32<<<g2, 256, 0, stream>>>(P3, 256, 256, nullptr, 0, 0, Wu2, 128, nullptr, nullptr, P1, 128, NVN);

  hipMemsetAsync(P3, 0, (size_t)NVN * 128 * 4, stream);
  hipMemsetAsync(P4, 0, (size_t)NUN * 128 * 4, stream);
  scatter_add_d128<<<sg, 256, 0, stream>>>(P2, edge_u, edge_v, P3, ne);
  scatter_add_d128<<<sg, 256, 0, stream>>>(P1, edge_v, edge_u, P4, ne);
  // ve2 -> out_v[:, 0:128] ; ue2 -> out_u[:, 0:128]
  finalize_mean_bias_prelu<<<rg, 256, 0, stream>>>(P3, dv, bv2, av2, out_v, 256, NVN);
  finalize_mean_bias_prelu<<<rg, 256, 0, stream>>>(P4, du, bu2, au2, out_u, 256, NUN);

  // ---- stage 3: ve3 = concat(ve2, features_v) @ Wv3 + bv3 -> P1 ; ue3 -> P2
  gemm_f32<<<g2, 256, 0, stream>>>(out_v, 256, 128, features_v, 128, 128, Wv3, 128, bv3, nullptr, P1, 128, NVN);
  gemm_f32<<<g2, 256, 0, stream>>>(out_u, 256, 128, features_u, 128, 128, Wu3, 128, bu3, nullptr, P2, 128, NUN);

  hipMemsetAsync(P3, 0, (size_t)NVN * 128 * 4, stream);
  hipMemsetAsync(P4, 0, (size_t)NUN * 128 * 4, stream);
  scatter_add_d128<<<sg, 256, 0, stream>>>(P2, edge_u, edge_v, P3, ne);
  scatter_add_d128<<<sg, 256, 0, stream>>>(P1, edge_v, edge_u, P4, ne);
  finalize_s3<<<rg, 256, 0, stream>>>(P3, P1, dv, out_v + 128, 256, NVN);
  finalize_s3<<<rg, 256, 0, stream>>>(P4, P2, du, out_u + 128, 256, NUN);
}

// Round 2
// 1125.143 us; speedup vs baseline: 7.4827x; 7.4827x over previous
//
#include <hip/hip_runtime.h>
#include <stdint.h>

#define NVN 50000
#define NUN 50000

// ------------------------------------------------------------- degree count
__global__ __launch_bounds__(256) void count_kernel(const int* __restrict__ ev,
                                                    const int* __restrict__ eu,
                                                    int* __restrict__ cnt_v,
                                                    int* __restrict__ cnt_u, int ne) {
  int i = blockIdx.x * 256 + threadIdx.x;
  if (i < ne) {
    atomicAdd(&cnt_v[ev[i]], 1);
    atomicAdd(&cnt_u[eu[i]], 1);
  }
}

// ------------------------------------------- exclusive scan (single block)
// reads cnt from `cur`, writes exclusive offsets to both `off` and `cur`
// (cur becomes the fill cursor). off[n] = total.
__global__ __launch_bounds__(1024) void scan_kernel(int* __restrict__ cur,
                                                    int* __restrict__ off, int n) {
  __shared__ int buf[1024];
  __shared__ int carry_s;
  const int tid = threadIdx.x;
  if (tid == 0) carry_s = 0;
  __syncthreads();
  for (int base = 0; base < n; base += 1024) {
    int i = base + tid;
    int v = (i < n) ? cur[i] : 0;
    buf[tid] = v;
    __syncthreads();
#pragma unroll
    for (int s = 1; s < 1024; s <<= 1) {
      int t = (tid >= s) ? buf[tid - s] : 0;
      __syncthreads();
      buf[tid] += t;
      __syncthreads();
    }
    int excl = carry_s + buf[tid] - v;
    if (i < n) {
      off[i] = excl;
      cur[i] = excl;
    }
    __syncthreads();
    if (tid == 1023) carry_s += buf[1023];
    __syncthreads();
  }
  if (tid == 0) off[n] = carry_s;
}

// ------------------------------------------------------------- CSR fill
__global__ __launch_bounds__(256) void fill_kernel(const int* __restrict__ ev,
                                                   const int* __restrict__ eu,
                                                   int* __restrict__ cur_v,
                                                   int* __restrict__ cur_u,
                                                   int* __restrict__ csr_v,
                                                   int* __restrict__ csr_u, int ne) {
  int i = blockIdx.x * 256 + threadIdx.x;
  if (i < ne) {
    int v = ev[i], u = eu[i];
    int pv = atomicAdd(&cur_v[v], 1);
    csr_v[pv] = u;
    int pu = atomicAdd(&cur_u[u], 1);
    csr_u[pu] = v;
  }
}

// --------------------------------------------------- gather-aggregate d=128
// One wave (64 lanes) per destination row; lane owns 2 columns (float2).
// MODE 0: dst = sum/max(deg,1)
// MODE 1: dst = prelu(sum/max(deg,1) + bias)
// MODE 2: dst = (sum + own) / (deg + 1)
template <int MODE>
__global__ __launch_bounds__(256) void gather128(
    const float* __restrict__ src, const int* __restrict__ csr,
    const int* __restrict__ off, const float* __restrict__ bias,
    const float* __restrict__ slope, const float* __restrict__ own,
    float* __restrict__ dst, int ldo, int n) {
  int wid = (int)((blockIdx.x * 256 + threadIdx.x) >> 6);
  if (wid >= n) return;
  int c = (threadIdx.x & 63) * 2;
  int s = off[wid], e = off[wid + 1];
  float ax = 0.f, ay = 0.f;
  int i = s;
  for (; i + 1 < e; i += 2) {
    int r0 = csr[i], r1 = csr[i + 1];
    float2 v0 = *reinterpret_cast<const float2*>(src + (size_t)r0 * 128 + c);
    float2 v1 = *reinterpret_cast<const float2*>(src + (size_t)r1 * 128 + c);
    ax += v0.x + v1.x;
    ay += v0.y + v1.y;
  }
  if (i < e) {
    int r0 = csr[i];
    float2 v0 = *reinterpret_cast<const float2*>(src + (size_t)r0 * 128 + c);
    ax += v0.x;
    ay += v0.y;
  }
  float deg = (float)(e - s);
  float2 o;
  if (MODE == 0) {
    float inv = 1.f / fmaxf(deg, 1.f);
    o.x = ax * inv;
    o.y = ay * inv;
  } else if (MODE == 1) {
    float inv = 1.f / fmaxf(deg, 1.f);
    float sl = slope[0];
    float2 b = *reinterpret_cast<const float2*>(bias + c);
    o.x = ax * inv + b.x;
    o.y = ay * inv + b.y;
    o.x = o.x >= 0.f ? o.x : o.x * sl;
    o.y = o.y >= 0.f ? o.y : o.y * sl;
  } else {
    float inv = 1.f / (deg + 1.f);
    float2 ow = *reinterpret_cast<const float2*>(own + (size_t)wid * 128 + c);
    o.x = (ax + ow.x) * inv;
    o.y = (ay + ow.y) * inv;
  }
  *reinterpret_cast<float2*>(dst + (size_t)wid * ldo + c) = o;
}

// ---------------------------------------------------------------- f32 GEMM
// C[M,N] = act(concat(A1,A2) @ W + bias). 64x64 tile, BK=16, 256 threads,
// 4x4 micro-tile per thread. K1,K2 multiples of 16; N multiple of 64.
__global__ __launch_bounds__(256) void gemm_f32(
    const float* __restrict__ A1, int lda1, int K1,
    const float* __restrict__ A2, int lda2, int K2,
    const float* __restrict__ W, int N,
    const float* __restrict__ bias, const float* __restrict__ slope,
    float* __restrict__ C, int ldc, int M) {
  __shared__ float As[16][64];
  __shared__ float Ws[16][64];
  const int K = K1 + K2;
  const int bm = blockIdx.y * 64;
  const int bn = blockIdx.x * 64;
  const int tid = threadIdx.x;
  const int tr = tid >> 4;   // 0..15
  const int tc = tid & 15;   // 0..15

  float acc[4][4];
#pragma unroll
  for (int i = 0; i < 4; ++i)
#pragma unroll
    for (int j = 0; j < 4; ++j) acc[i][j] = 0.f;

  const int ar = tid >> 2;        // 0..63 (row in tile)
  const int ak = (tid & 3) * 4;   // 0,4,8,12
  const int wk = tid >> 4;        // 0..15
  const int wn = (tid & 15) * 4;  // 0..60

  for (int k0 = 0; k0 < K; k0 += 16) {
    float4 av = make_float4(0.f, 0.f, 0.f, 0.f);
    int row = bm + ar;
    if (row < M) {
      int kg = k0 + ak;
      if (kg < K1)
        av = *reinterpret_cast<const float4*>(A1 + (size_t)row * lda1 + kg);
      else
        av = *reinterpret_cast<const float4*>(A2 + (size_t)row * lda2 + (kg - K1));
    }
    As[ak + 0][ar] = av.x;
    As[ak + 1][ar] = av.y;
    As[ak + 2][ar] = av.z;
    As[ak + 3][ar] = av.w;
    const float4 wv =
        *reinterpret_cast<const float4*>(W + (size_t)(k0 + wk) * N + bn + wn);
    *reinterpret_cast<float4*>(&Ws[wk][wn]) = wv;
    __syncthreads();
#pragma unroll
    for (int kk = 0; kk < 16; ++kk) {
      float a[4], b[4];
#pragma unroll
      for (int i = 0; i < 4; ++i) a[i] = As[kk][tr * 4 + i];
#pragma unroll
      for (int j = 0; j < 4; ++j) b[j] = Ws[kk][tc * 4 + j];
#pragma unroll
      for (int i = 0; i < 4; ++i)
#pragma unroll
        for (int j = 0; j < 4; ++j) acc[i][j] = fmaf(a[i], b[j], acc[i][j]);
    }
    __syncthreads();
  }
  const bool has_act = (slope != nullptr);
  const float s = has_act ? slope[0] : 1.0f;
#pragma unroll
  for (int i = 0; i < 4; ++i) {
    int row = bm + tr * 4 + i;
    if (row >= M) continue;
#pragma unroll
    for (int j = 0; j < 4; ++j) {
      int col = bn + tc * 4 + j;
      float v = acc[i][j] + (bias ? bias[col] : 0.f);
      if (has_act && v < 0.f) v *= s;
      C[(size_t)row * ldc + col] = v;
    }
  }
}

extern "C" void kernel_launch(void* const* d_in, const int* in_sizes, int n_in,
                              void* d_out, int out_size, void* d_ws, size_t ws_size,
                              hipStream_t stream) {
  const float* features_v = (const float*)d_in[0];
  const float* features_u = (const float*)d_in[1];
  const int* edge_v = (const int*)d_in[2];
  const int* edge_u = (const int*)d_in[3];
  const float* Wv1 = (const float*)d_in[4];
  const float* bv1 = (const float*)d_in[5];
  const float* av1 = (const float*)d_in[6];
  const float* Wu1 = (const float*)d_in[7];
  const float* bu1 = (const float*)d_in[8];
  const float* au1 = (const float*)d_in[9];
  const float* Wv2 = (const float*)d_in[10];
  const float* bv2 = (const float*)d_in[11];
  const float* av2 = (const float*)d_in[12];
  const float* Wu2 = (const float*)d_in[13];
  const float* bu2 = (const float*)d_in[14];
  const float* au2 = (const float*)d_in[15];
  const float* Wv3 = (const float*)d_in[16];
  const float* bv3 = (const float*)d_in[17];
  const float* Wu3 = (const float*)d_in[18];
  const float* bu3 = (const float*)d_in[19];
  const int ne = in_sizes[2];

  // ---- workspace layout
  int* cur_v = (int*)d_ws;                 // [NV] counts -> cursors
  int* cur_u = cur_v + NVN;                // [NU]
  int* off_v = cur_u + NUN;                // [NV+1]
  int* off_u = off_v + NVN + 1;            // [NU+1]
  int* csr_v = off_u + NUN + 1;            // [ne]  (u indices, grouped by v)
  int* csr_u = csr_v + ne;                 // [ne]  (v indices, grouped by u)
  uintptr_t fbase = (((uintptr_t)(csr_u + ne)) + 15) & ~(uintptr_t)15;
  float* P1 = (float*)fbase;               // [NV*128]
  float* P2 = P1 + (size_t)NVN * 128;      // [NU*128]
  float* P3 = P2 + (size_t)NUN * 128;      // [N*256] (ve1 then ue1)

  float* out_v = (float*)d_out;             // [NV,256]
  float* out_u = out_v + (size_t)NVN * 256; // [NU,256]

  const int eg = (ne + 255) / 256;
  const int gg = (NVN + 3) / 4;  // 4 waves/block, 1 wave/node (NV==NU)
  const dim3 g1(256 / 64, (NVN + 63) / 64);
  const dim3 g2(128 / 64, (NVN + 63) / 64);

  // ---- CSR build
  hipMemsetAsync(cur_v, 0, (size_t)(NVN + NUN) * 4, stream);
  count_kernel<<<eg, 256, 0, stream>>>(edge_v, edge_u, cur_v, cur_u, ne);
  scan_kernel<<<1, 1024, 0, stream>>>(cur_v, off_v, NVN);
  scan_kernel<<<1, 1024, 0, stream>>>(cur_u, off_u, NUN);
  fill_kernel<<<eg, 256, 0, stream>>>(edge_v, edge_u, cur_v, cur_u, csr_v, csr_u, ne);

  // ---- stage 1: neighbor means of raw features
  gather128<0><<<gg, 256, 0, stream>>>(features_u, csr_v, off_v, nullptr, nullptr,
                                       nullptr, P1, 128, NVN);
  gather128<0><<<gg, 256, 0, stream>>>(features_v, csr_u, off_u, nullptr, nullptr,
                                       nullptr, P2, 128, NUN);

  // ve1 = prelu(P1@Wv1+bv1) -> P3 ; then t_v = ve1@Wu2 -> P1 (P1 free after)
  gemm_f32<<<g1, 256, 0, stream>>>(P1, 128, 128, nullptr, 0, 0, Wv1, 256, bv1, av1, P3, 256, NVN);
  gemm_f32<<<g2, 256, 0, stream>>>(P3, 256, 256, nullptr, 0, 0, Wu2, 128, nullptr, nullptr, P1, 128, NVN);
  // ue1 = prelu(P2@Wu1+bu1) -> P3 ; then t_u = ue1@Wv2 -> P2
  gemm_f32<<<g1, 256, 0, stream>>>(P2, 128, 128, nullptr, 0, 0, Wu1, 256, bu1, au1, P3, 256, NUN);
  gemm_f32<<<g2, 256, 0, stream>>>(P3, 256, 256, nullptr, 0, 0, Wv2, 128, nullptr, nullptr, P2, 128, NUN);

  // ---- stage 2: ve2 = prelu(mean_gather(t_u) + bv2) -> out_v[:,0:128]
  gather128<1><<<gg, 256, 0, stream>>>(P2, csr_v, off_v, bv2, av2, nullptr, out_v, 256, NVN);
  gather128<1><<<gg, 256, 0, stream>>>(P1, csr_u, off_u, bu2, au2, nullptr, out_u, 256, NUN);

  // ---- stage 3: ve3 = concat(ve2, fv)@Wv3+bv3 -> P1 ; ue3 -> P2
  gemm_f32<<<g2, 256, 0, stream>>>(out_v, 256, 128, features_v, 128, 128, Wv3, 128, bv3, nullptr, P1, 128, NVN);
  gemm_f32<<<g2, 256, 0, stream>>>(out_u, 256, 128, features_u, 128, 128, Wu3, 128, bu3, nullptr, P2, 128, NUN);

  // sv = (gather_sum(ue3) + ve3) / (deg_v+1) -> out_v[:,128:256]
  gather128<2><<<gg, 256, 0, stream>>>(P2, csr_v, off_v, nullptr, nullptr, P1, out_v + 128, 256, NVN);
  gather128<2><<<gg, 256, 0, stream>>>(P1, csr_u, off_u, nullptr, nullptr, P2, out_u + 128, 256, NUN);
}

// Round 3
// 835.502 us; speedup vs baseline: 10.0767x; 1.3467x over previous
//
#include <hip/hip_runtime.h>
#include <stdint.h>

#define NVN 50000
#define NUN 50000

typedef __attribute__((ext_vector_type(8))) short short8v;
typedef __attribute__((ext_vector_type(4))) float float4v;

__device__ __forceinline__ unsigned short f2bf(float f) {
  union { float f; unsigned u; } x; x.f = f;
  unsigned r = x.u + 0x7FFFu + ((x.u >> 16) & 1u);
  return (unsigned short)(r >> 16);
}
__device__ __forceinline__ float bf2f(unsigned short h) {
  union { unsigned u; float f; } x; x.u = ((unsigned)h) << 16;
  return x.f;
}

// ------------------------------------------------------------- degree count
__global__ __launch_bounds__(256) void count_kernel(const int* __restrict__ ev,
                                                    const int* __restrict__ eu,
                                                    int* __restrict__ cnt_v,
                                                    int* __restrict__ cnt_u, int ne) {
  int i = blockIdx.x * 256 + threadIdx.x;
  if (i < ne) {
    atomicAdd(&cnt_v[ev[i]], 1);
    atomicAdd(&cnt_u[eu[i]], 1);
  }
}

// ---------------------- exclusive scan, wave-shuffle based; 2 blocks (v,u)
__global__ __launch_bounds__(1024) void scan_kernel(int* __restrict__ cur_v,
                                                    int* __restrict__ off_v, int n_v,
                                                    int* __restrict__ cur_u,
                                                    int* __restrict__ off_u, int n_u) {
  int* cur = blockIdx.x ? cur_u : cur_v;
  int* off = blockIdx.x ? off_u : off_v;
  const int n = blockIdx.x ? n_u : n_v;
  __shared__ int wsum[16];
  __shared__ int carry_s;
  const int tid = threadIdx.x;
  const int lane = tid & 63;
  const int w = tid >> 6;
  if (tid == 0) carry_s = 0;
  __syncthreads();
  for (int base = 0; base < n; base += 1024) {
    int i = base + tid;
    int v = (i < n) ? cur[i] : 0;
    int x = v;  // inclusive wave scan
#pragma unroll
    for (int s = 1; s < 64; s <<= 1) {
      int t = __shfl_up(x, (unsigned)s, 64);
      if (lane >= s) x += t;
    }
    if (lane == 63) wsum[w] = x;
    __syncthreads();
    if (w == 0) {
      int y = (lane < 16) ? wsum[lane] : 0;
#pragma unroll
      for (int s = 1; s < 16; s <<= 1) {
        int t = __shfl_up(y, (unsigned)s, 64);
        if (lane >= s) y += t;
      }
      if (lane < 16) wsum[lane] = y;
    }
    __syncthreads();
    int wbase = (w ? wsum[w - 1] : 0) + carry_s;
    int excl = wbase + x - v;
    if (i < n) { off[i] = excl; cur[i] = excl; }
    __syncthreads();
    if (tid == 1023) carry_s = wbase + x;
    __syncthreads();
  }
  if (tid == 0) off[n] = carry_s;
}

// ------------------------------------------------------------- CSR fill
__global__ __launch_bounds__(256) void fill_kernel(const int* __restrict__ ev,
                                                   const int* __restrict__ eu,
                                                   int* __restrict__ cur_v,
                                                   int* __restrict__ cur_u,
                                                   int* __restrict__ csr_v,
                                                   int* __restrict__ csr_u, int ne) {
  int i = blockIdx.x * 256 + threadIdx.x;
  if (i < ne) {
    int v = ev[i], u = eu[i];
    int pv = atomicAdd(&cur_v[v], 1);
    csr_v[pv] = u;
    int pu = atomicAdd(&cur_u[u], 1);
    csr_u[pu] = v;
  }
}

// -------------------------------------------------- weight convert+transpose
struct WConvEnt { const float* src; unsigned short* dst; int K; int N; };
struct WConvArr { WConvEnt w[6]; };
__global__ __launch_bounds__(256) void convert_weights(WConvArr a) {
  WConvEnt c = a.w[blockIdx.y];
  int i = blockIdx.x * 256 + threadIdx.x;
  int total = c.K * c.N;
  if (i < total) {
    int k = i / c.N, n = i - k * c.N;
    c.dst[(size_t)n * c.K + k] = f2bf(c.src[i]);  // Wt[N][K]
  }
}

// --------------------------------------------------- gather-aggregate d=128
// One wave per destination row; lane owns 2 columns. blockIdx.y picks side.
// MODE 0: dst = sum/max(deg,1)        MODE 1: prelu(sum/max(deg,1)+bias)
// MODE 2: dst = (sum + own)/(deg+1)
struct GSide {
  const void* src; const int* csr; const int* off;
  const float* bias; const float* slope; const float* own;
  void* dst; int ldo;
};
template <int MODE, int SRCBF, int OUTBF>
__global__ __launch_bounds__(256) void gatherk(GSide g0, GSide g1, int n) {
  GSide g = blockIdx.y ? g1 : g0;
  int wid = (int)(((size_t)blockIdx.x * 256 + threadIdx.x) >> 6);
  if (wid >= n) return;
  const int lane = threadIdx.x & 63;
  const int s = g.off[wid], e = g.off[wid + 1];
  float ax = 0.f, ay = 0.f;
  if (SRCBF) {
    const unsigned* src = (const unsigned*)g.src;  // row = 64 uints
    int i = s;
    for (; i + 1 < e; i += 2) {
      unsigned p0 = src[(size_t)g.csr[i] * 64 + lane];
      unsigned p1 = src[(size_t)g.csr[i + 1] * 64 + lane];
      ax += bf2f((unsigned short)p0) + bf2f((unsigned short)p1);
      ay += bf2f((unsigned short)(p0 >> 16)) + bf2f((unsigned short)(p1 >> 16));
    }
    if (i < e) {
      unsigned p0 = src[(size_t)g.csr[i] * 64 + lane];
      ax += bf2f((unsigned short)p0);
      ay += bf2f((unsigned short)(p0 >> 16));
    }
  } else {
    const float* src = (const float*)g.src;
    const int c = lane * 2;
    int i = s;
    for (; i + 1 < e; i += 2) {
      float2 v0 = *(const float2*)(src + (size_t)g.csr[i] * 128 + c);
      float2 v1 = *(const float2*)(src + (size_t)g.csr[i + 1] * 128 + c);
      ax += v0.x + v1.x; ay += v0.y + v1.y;
    }
    if (i < e) {
      float2 v0 = *(const float2*)(src + (size_t)g.csr[i] * 128 + c);
      ax += v0.x; ay += v0.y;
    }
  }
  const float deg = (float)(e - s);
  float ox, oy;
  if (MODE == 0) {
    float inv = 1.f / fmaxf(deg, 1.f);
    ox = ax * inv; oy = ay * inv;
  } else if (MODE == 1) {
    float inv = 1.f / fmaxf(deg, 1.f);
    float sl = g.slope[0];
    float2 b = *(const float2*)(g.bias + lane * 2);
    ox = ax * inv + b.x; oy = ay * inv + b.y;
    ox = ox >= 0.f ? ox : ox * sl;
    oy = oy >= 0.f ? oy : oy * sl;
  } else {
    float inv = 1.f / (deg + 1.f);
    float2 ow = *(const float2*)(g.own + (size_t)wid * 128 + lane * 2);
    ox = (ax + ow.x) * inv; oy = (ay + ow.y) * inv;
  }
  if (OUTBF) {
    unsigned pv = ((unsigned)f2bf(oy) << 16) | (unsigned)f2bf(ox);
    ((unsigned*)g.dst)[(size_t)wid * (g.ldo / 2) + lane] = pv;
  } else {
    *(float2*)((float*)g.dst + (size_t)wid * g.ldo + lane * 2) = make_float2(ox, oy);
  }
}

// ---------------------------------------------------------------- MFMA GEMM
// C[M,N] = act(concat(A1,A2) @ W + bias), W pre-transposed bf16 [N][K].
// Block: 4 waves x 16 rows = 64 rows; each wave covers all N (NT = N/16
// fragments of 16x16x32). blockIdx.z picks the v/u side.
struct GmSide {
  const void* A1; const void* A2;
  const unsigned short* Wt;
  const float* bias; const float* slope;
  void* C;
};

template <int BF>
__device__ __forceinline__ short8v load_a8(const void* A, size_t off) {
  if (BF) {
    return *(const short8v*)((const unsigned short*)A + off);
  } else {
    const float* p = (const float*)A + off;
    float4 x = *(const float4*)p;
    float4 y = *(const float4*)(p + 4);
    short8v r;
    r[0] = (short)f2bf(x.x); r[1] = (short)f2bf(x.y);
    r[2] = (short)f2bf(x.z); r[3] = (short)f2bf(x.w);
    r[4] = (short)f2bf(y.x); r[5] = (short)f2bf(y.y);
    r[6] = (short)f2bf(y.z); r[7] = (short)f2bf(y.w);
    return r;
  }
}

template <int NT, int A1BF, int A2BF, int CBF, int ACT>
__global__ __launch_bounds__(256) void gemm_mfma(GmSide s0, GmSide s1,
                                                 int lda1, int K1, int lda2, int K2,
                                                 int ldc, int M) {
  GmSide s = blockIdx.z ? s1 : s0;
  const int K = K1 + K2;
  const int tid = threadIdx.x;
  const int wv = tid >> 6;
  const int lane = tid & 63;
  const int lc = lane & 15;
  const int khi = lane >> 4;
  const int bm = blockIdx.y * 64;
  const int rowa = bm + wv * 16 + lc;

  float4v acc[NT];
#pragma unroll
  for (int i = 0; i < NT; ++i) acc[i] = (float4v){0.f, 0.f, 0.f, 0.f};

  for (int kb = 0; kb < K; kb += 32) {
    const int kg = kb + khi * 8;
    short8v a = (short8v){0, 0, 0, 0, 0, 0, 0, 0};
    if (rowa < M) {
      if (kg < K1) a = load_a8<A1BF>(s.A1, (size_t)rowa * lda1 + kg);
      else         a = load_a8<A2BF>(s.A2, (size_t)rowa * lda2 + (kg - K1));
    }
#pragma unroll
    for (int fn = 0; fn < NT; ++fn) {
      const short8v b = *(const short8v*)(s.Wt + (size_t)(fn * 16 + lc) * K + kg);
      acc[fn] = __builtin_amdgcn_mfma_f32_16x16x32_bf16(a, b, acc[fn], 0, 0, 0);
    }
  }
  const float sl = ACT ? s.slope[0] : 0.f;
#pragma unroll
  for (int fn = 0; fn < NT; ++fn) {
    const int col = fn * 16 + lc;
    const float bv = s.bias ? s.bias[col] : 0.f;
#pragma unroll
    for (int i = 0; i < 4; ++i) {
      const int row = bm + wv * 16 + khi * 4 + i;
      if (row >= M) continue;
      float v = acc[fn][i] + bv;
      if (ACT && v < 0.f) v *= sl;
      if (CBF) ((unsigned short*)s.C)[(size_t)row * ldc + col] = f2bf(v);
      else     ((float*)s.C)[(size_t)row * ldc + col] = v;
    }
  }
}

extern "C" void kernel_launch(void* const* d_in, const int* in_sizes, int n_in,
                              void* d_out, int out_size, void* d_ws, size_t ws_size,
                              hipStream_t stream) {
  const float* features_v = (const float*)d_in[0];
  const float* features_u = (const float*)d_in[1];
  const int* edge_v = (const int*)d_in[2];
  const int* edge_u = (const int*)d_in[3];
  const float* Wv1 = (const float*)d_in[4];
  const float* bv1 = (const float*)d_in[5];
  const float* av1 = (const float*)d_in[6];
  const float* Wu1 = (const float*)d_in[7];
  const float* bu1 = (const float*)d_in[8];
  const float* au1 = (const float*)d_in[9];
  const float* Wv2 = (const float*)d_in[10];
  const float* bv2 = (const float*)d_in[11];
  const float* av2 = (const float*)d_in[12];
  const float* Wu2 = (const float*)d_in[13];
  const float* bu2 = (const float*)d_in[14];
  const float* au2 = (const float*)d_in[15];
  const float* Wv3 = (const float*)d_in[16];
  const float* bv3 = (const float*)d_in[17];
  const float* Wu3 = (const float*)d_in[18];
  const float* bu3 = (const float*)d_in[19];
  const int ne = in_sizes[2];

  // ---- workspace layout
  int* cur_v = (int*)d_ws;                 // [NV]
  int* cur_u = cur_v + NVN;                // [NU]
  int* off_v = cur_u + NUN;                // [NV+1]
  int* off_u = off_v + NVN + 1;            // [NU+1]
  int* csr_v = off_u + NUN + 1;            // [ne]
  int* csr_u = csr_v + ne;                 // [ne]
  uintptr_t hbase = (((uintptr_t)(csr_u + ne)) + 15) & ~(uintptr_t)15;
  unsigned short* P1b = (unsigned short*)hbase;      // [NV*128] bf16 (alias Tv)
  unsigned short* P2b = P1b + (size_t)NVN * 128;     // [NU*128] bf16 (alias Tu)
  unsigned short* E1v = P2b + (size_t)NUN * 128;     // [NV*256] bf16 (alias Ve3 f32)
  unsigned short* E1u = E1v + (size_t)NVN * 256;     // [NU*256] bf16 (alias Ue3 f32)
  unsigned short* Wb = E1u + (size_t)NUN * 256;      // 6 * 32768 bf16
  float* Ve3 = (float*)E1v;  // [NV*128] f32
  float* Ue3 = (float*)E1u;  // [NU*128] f32

  float* out_v = (float*)d_out;              // [NV,256]
  float* out_u = out_v + (size_t)NVN * 256;  // [NU,256]

  const int eg = (ne + 255) / 256;
  const dim3 gg((NVN * 64) / 256, 2);        // one wave per node, 2 sides
  const dim3 gm(1, (NVN + 63) / 64, 2);      // 64 rows/block, 2 sides

  // ---- CSR build + weight conversion
  hipMemsetAsync(cur_v, 0, (size_t)(NVN + NUN) * 4, stream);
  WConvArr wc;
  wc.w[0] = {Wv1, Wb + 0 * 32768, 128, 256};
  wc.w[1] = {Wu1, Wb + 1 * 32768, 128, 256};
  wc.w[2] = {Wv2, Wb + 2 * 32768, 256, 128};
  wc.w[3] = {Wu2, Wb + 3 * 32768, 256, 128};
  wc.w[4] = {Wv3, Wb + 4 * 32768, 256, 128};
  wc.w[5] = {Wu3, Wb + 5 * 32768, 256, 128};
  convert_weights<<<dim3(128, 6), 256, 0, stream>>>(wc);
  count_kernel<<<eg, 256, 0, stream>>>(edge_v, edge_u, cur_v, cur_u, ne);
  scan_kernel<<<2, 1024, 0, stream>>>(cur_v, off_v, NVN, cur_u, off_u, NUN);
  fill_kernel<<<eg, 256, 0, stream>>>(edge_v, edge_u, cur_v, cur_u, csr_v, csr_u, ne);

  // ---- stage 1: neighbor means of raw features (f32 src -> bf16 dst)
  {
    GSide a{features_u, csr_v, off_v, nullptr, nullptr, nullptr, P1b, 128};
    GSide b{features_v, csr_u, off_u, nullptr, nullptr, nullptr, P2b, 128};
    gatherk<0, 0, 1><<<gg, 256, 0, stream>>>(a, b, NVN);
  }
  // ve1 = prelu(P1b@Wv1+bv1) -> E1v ; ue1 -> E1u   (N=256, K=128)
  {
    GmSide a{P1b, nullptr, Wb + 0 * 32768, bv1, av1, E1v};
    GmSide b{P2b, nullptr, Wb + 1 * 32768, bu1, au1, E1u};
    gemm_mfma<16, 1, 0, 1, 1><<<gm, 256, 0, stream>>>(a, b, 128, 128, 0, 0, 256, NVN);
  }
  // t_v = ve1@Wu2 -> Tv(P1b) ; t_u = ue1@Wv2 -> Tu(P2b)   (N=128, K=256)
  {
    GmSide a{E1v, nullptr, Wb + 3 * 32768, nullptr, nullptr, P1b};
    GmSide b{E1u, nullptr, Wb + 2 * 32768, nullptr, nullptr, P2b};
    gemm_mfma<8, 1, 0, 1, 0><<<gm, 256, 0, stream>>>(a, b, 256, 256, 0, 0, 128, NVN);
  }
  // ---- stage 2: ve2 = prelu(mean_gather(Tu) + bv2) -> out_v[:,0:128]
  {
    GSide a{P2b, csr_v, off_v, bv2, av2, nullptr, out_v, 256};
    GSide b{P1b, csr_u, off_u, bu2, au2, nullptr, out_u, 256};
    gatherk<1, 1, 0><<<gg, 256, 0, stream>>>(a, b, NVN);
  }
  // ---- stage 3: ve3 = concat(ve2, fv)@Wv3+bv3 -> Ve3 (f32)
  {
    GmSide a{out_v, features_v, Wb + 4 * 32768, bv3, nullptr, Ve3};
    GmSide b{out_u, features_u, Wb + 5 * 32768, bu3, nullptr, Ue3};
    gemm_mfma<8, 0, 0, 0, 0><<<gm, 256, 0, stream>>>(a, b, 256, 128, 128, 128, 128, NVN);
  }
  // sv = (gather_sum(Ue3) + Ve3)/(deg_v+1) -> out_v[:,128:256]
  {
    GSide a{Ue3, csr_v, off_v, nullptr, nullptr, Ve3, out_v + 128, 256};
    GSide b{Ve3, csr_u, off_u, nullptr, nullptr, Ue3, out_u + 128, 256};
    gatherk<2, 0, 0><<<gg, 256, 0, stream>>>(a, b, NVN);
  }
}

// Round 4
// 705.198 us; speedup vs baseline: 11.9386x; 1.1848x over previous
//
#include <hip/hip_runtime.h>
#include <stdint.h>

#define NVN 50000
#define NUN 50000

typedef __attribute__((ext_vector_type(8))) short short8v;
typedef __attribute__((ext_vector_type(8))) unsigned short ushort8v;
typedef __attribute__((ext_vector_type(4))) float float4v;

__device__ __forceinline__ unsigned short f2bf(float f) {
  union { float f; unsigned u; } x; x.f = f;
  unsigned r = x.u + 0x7FFFu + ((x.u >> 16) & 1u);
  return (unsigned short)(r >> 16);
}
__device__ __forceinline__ float bf2f(unsigned short h) {
  union { unsigned u; float f; } x; x.u = ((unsigned)h) << 16;
  return x.f;
}

// ---------------- prep: weight convert+transpose, feature f32->bf16, count
struct WConvEnt { const float* src; unsigned short* dst; int K; int N; };
struct PrepArgs {
  WConvEnt w[6];                       // all 32768 elements each
  const float* fv; const float* fu;
  unsigned short* fbv; unsigned short* fbu;
  const int* ev; const int* eu;
  int* cnt_v; int* cnt_u; int ne;
};
__global__ __launch_bounds__(256) void prep_kernel(PrepArgs a) {
  int b = blockIdx.x;
  if (b < 768) {  // 6 weights x 128 blocks
    WConvEnt c = a.w[b >> 7];
    int i = (b & 127) * 256 + threadIdx.x;
    int k = i / c.N, n = i - k * c.N;
    c.dst[(size_t)n * c.K + k] = f2bf(c.src[i]);  // Wt[N][K]
    return;
  }
  b -= 768;
  if (b < 6250) {  // features: 3125 blocks per side, 8 elems/thread
    const float* src = (b < 3125) ? a.fv : a.fu;
    unsigned short* dst = (b < 3125) ? a.fbv : a.fbu;
    int bb = (b < 3125) ? b : b - 3125;
    size_t base = ((size_t)bb * 256 + threadIdx.x) * 8;
    float4 x = *(const float4*)(src + base);
    float4 y = *(const float4*)(src + base + 4);
    ushort8v r;
    r[0] = f2bf(x.x); r[1] = f2bf(x.y); r[2] = f2bf(x.z); r[3] = f2bf(x.w);
    r[4] = f2bf(y.x); r[5] = f2bf(y.y); r[6] = f2bf(y.z); r[7] = f2bf(y.w);
    *(ushort8v*)(dst + base) = r;
    return;
  }
  b -= 6250;
  int i = b * 256 + threadIdx.x;
  if (i < a.ne) {
    atomicAdd(&a.cnt_v[a.ev[i]], 1);
    atomicAdd(&a.cnt_u[a.eu[i]], 1);
  }
}

// ---------------------- exclusive scan, wave-shuffle based; 2 blocks (v,u)
__global__ __launch_bounds__(1024) void scan_kernel(int* __restrict__ cur_v,
                                                    int* __restrict__ off_v, int n_v,
                                                    int* __restrict__ cur_u,
                                                    int* __restrict__ off_u, int n_u) {
  int* cur = blockIdx.x ? cur_u : cur_v;
  int* off = blockIdx.x ? off_u : off_v;
  const int n = blockIdx.x ? n_u : n_v;
  __shared__ int wsum[16];
  __shared__ int carry_s;
  const int tid = threadIdx.x;
  const int lane = tid & 63;
  const int w = tid >> 6;
  if (tid == 0) carry_s = 0;
  __syncthreads();
  for (int base = 0; base < n; base += 1024) {
    int i = base + tid;
    int v = (i < n) ? cur[i] : 0;
    int x = v;
#pragma unroll
    for (int s = 1; s < 64; s <<= 1) {
      int t = __shfl_up(x, (unsigned)s, 64);
      if (lane >= s) x += t;
    }
    if (lane == 63) wsum[w] = x;
    __syncthreads();
    if (w == 0) {
      int y = (lane < 16) ? wsum[lane] : 0;
#pragma unroll
      for (int s = 1; s < 16; s <<= 1) {
        int t = __shfl_up(y, (unsigned)s, 64);
        if (lane >= s) y += t;
      }
      if (lane < 16) wsum[lane] = y;
    }
    __syncthreads();
    int wbase = (w ? wsum[w - 1] : 0) + carry_s;
    int excl = wbase + x - v;
    if (i < n) { off[i] = excl; cur[i] = excl; }
    __syncthreads();
    if (tid == 1023) carry_s = wbase + x;
    __syncthreads();
  }
  if (tid == 0) off[n] = carry_s;
}

// ------------------------------------------------------------- CSR fill
__global__ __launch_bounds__(256) void fill_kernel(const int* __restrict__ ev,
                                                   const int* __restrict__ eu,
                                                   int* __restrict__ cur_v,
                                                   int* __restrict__ cur_u,
                                                   unsigned short* __restrict__ csr_v,
                                                   unsigned short* __restrict__ csr_u,
                                                   int ne) {
  int i = blockIdx.x * 256 + threadIdx.x;
  if (i < ne) {
    int v = ev[i], u = eu[i];
    int pv = atomicAdd(&cur_v[v], 1);
    csr_v[pv] = (unsigned short)u;
    int pu = atomicAdd(&cur_u[u], 1);
    csr_u[pu] = (unsigned short)v;
  }
}

// --------------------------------------------------- gather-aggregate d=128
// One wave per destination row; lane owns 2 columns (one bf16x2 uint).
// All sources bf16. MODE 0: bf16 dst = sum/max(deg,1)
// MODE 1: f32 dst = prelu(sum/max(deg,1)+bias)
// MODE 2: f32 dst = (sum + own_bf16)/(deg+1)
struct GSide {
  const unsigned* src;             // bf16x2 rows, 64 uints/row
  const unsigned short* csr; const int* off;
  const float* bias; const float* slope;
  const unsigned* own;             // bf16x2 rows (mode 2)
  void* dst; int ldo;              // ldo in dst elements
};
template <int MODE>
__global__ __launch_bounds__(256) void gatherk(GSide g0, GSide g1, int n) {
  GSide g = blockIdx.y ? g1 : g0;
  int wid = (int)(((size_t)blockIdx.x * 256 + threadIdx.x) >> 6);
  if (wid >= n) return;
  const int lane = threadIdx.x & 63;
  const int s = g.off[wid], e = g.off[wid + 1];
  float ax = 0.f, ay = 0.f;
  int i = s;
  for (; i + 3 < e; i += 4) {
    unsigned p0 = g.src[(size_t)g.csr[i] * 64 + lane];
    unsigned p1 = g.src[(size_t)g.csr[i + 1] * 64 + lane];
    unsigned p2 = g.src[(size_t)g.csr[i + 2] * 64 + lane];
    unsigned p3 = g.src[(size_t)g.csr[i + 3] * 64 + lane];
    ax += bf2f((unsigned short)p0) + bf2f((unsigned short)p1) +
          bf2f((unsigned short)p2) + bf2f((unsigned short)p3);
    ay += bf2f((unsigned short)(p0 >> 16)) + bf2f((unsigned short)(p1 >> 16)) +
          bf2f((unsigned short)(p2 >> 16)) + bf2f((unsigned short)(p3 >> 16));
  }
  for (; i < e; ++i) {
    unsigned p0 = g.src[(size_t)g.csr[i] * 64 + lane];
    ax += bf2f((unsigned short)p0);
    ay += bf2f((unsigned short)(p0 >> 16));
  }
  const float deg = (float)(e - s);
  if (MODE == 0) {
    float inv = 1.f / fmaxf(deg, 1.f);
    unsigned pv = ((unsigned)f2bf(ay * inv) << 16) | (unsigned)f2bf(ax * inv);
    ((unsigned*)g.dst)[(size_t)wid * g.ldo + lane] = pv;
  } else if (MODE == 1) {
    float inv = 1.f / fmaxf(deg, 1.f);
    float sl = g.slope[0];
    float2 b = *(const float2*)(g.bias + lane * 2);
    float ox = ax * inv + b.x, oy = ay * inv + b.y;
    ox = ox >= 0.f ? ox : ox * sl;
    oy = oy >= 0.f ? oy : oy * sl;
    *(float2*)((float*)g.dst + (size_t)wid * g.ldo + lane * 2) = make_float2(ox, oy);
  } else {
    float inv = 1.f / (deg + 1.f);
    unsigned ow = g.own[(size_t)wid * 64 + lane];
    float ox = (ax + bf2f((unsigned short)ow)) * inv;
    float oy = (ay + bf2f((unsigned short)(ow >> 16))) * inv;
    *(float2*)((float*)g.dst + (size_t)wid * g.ldo + lane * 2) = make_float2(ox, oy);
  }
}

// ---------------------------------------------------------------- MFMA GEMM
// C[M,N] = act(concat(A1,A2) @ W + bias), W pre-transposed bf16 [N][K].
// Block: 4 waves x 16 rows = 64 rows; wave covers all N (NT fragments).
struct GmSide {
  const void* A1; const void* A2;
  const unsigned short* Wt;
  const float* bias; const float* slope;
  void* C;
};

template <int BF>
__device__ __forceinline__ short8v load_a8(const void* A, size_t off) {
  if (BF) {
    return *(const short8v*)((const unsigned short*)A + off);
  } else {
    const float* p = (const float*)A + off;
    float4 x = *(const float4*)p;
    float4 y = *(const float4*)(p + 4);
    short8v r;
    r[0] = (short)f2bf(x.x); r[1] = (short)f2bf(x.y);
    r[2] = (short)f2bf(x.z); r[3] = (short)f2bf(x.w);
    r[4] = (short)f2bf(y.x); r[5] = (short)f2bf(y.y);
    r[6] = (short)f2bf(y.z); r[7] = (short)f2bf(y.w);
    return r;
  }
}

template <int NT, int A1BF, int A2BF, int CBF, int ACT>
__global__ __launch_bounds__(256) void gemm_mfma(GmSide s0, GmSide s1,
                                                 int lda1, int K1, int lda2, int K2,
                                                 int ldc, int M) {
  GmSide s = blockIdx.z ? s1 : s0;
  const int K = K1 + K2;
  const int tid = threadIdx.x;
  const int wv = tid >> 6;
  const int lane = tid & 63;
  const int lc = lane & 15;
  const int khi = lane >> 4;
  const int bm = blockIdx.y * 64;
  const int rowa = bm + wv * 16 + lc;

  float4v acc[NT];
#pragma unroll
  for (int i = 0; i < NT; ++i) acc[i] = (float4v){0.f, 0.f, 0.f, 0.f};

  for (int kb = 0; kb < K; kb += 32) {
    const int kg = kb + khi * 8;
    short8v a = (short8v){0, 0, 0, 0, 0, 0, 0, 0};
    if (rowa < M) {
      if (kg < K1) a = load_a8<A1BF>(s.A1, (size_t)rowa * lda1 + kg);
      else         a = load_a8<A2BF>(s.A2, (size_t)rowa * lda2 + (kg - K1));
    }
#pragma unroll
    for (int fn = 0; fn < NT; ++fn) {
      const short8v b = *(const short8v*)(s.Wt + (size_t)(fn * 16 + lc) * K + kg);
      acc[fn] = __builtin_amdgcn_mfma_f32_16x16x32_bf16(a, b, acc[fn], 0, 0, 0);
    }
  }
  const float sl = ACT ? s.slope[0] : 0.f;
#pragma unroll
  for (int fn = 0; fn < NT; ++fn) {
    const int col = fn * 16 + lc;
    const float bv = s.bias ? s.bias[col] : 0.f;
#pragma unroll
    for (int i = 0; i < 4; ++i) {
      const int row = bm + wv * 16 + khi * 4 + i;
      if (row >= M) continue;
      float v = acc[fn][i] + bv;
      if (ACT && v < 0.f) v *= sl;
      if (CBF) ((unsigned short*)s.C)[(size_t)row * ldc + col] = f2bf(v);
      else     ((float*)s.C)[(size_t)row * ldc + col] = v;
    }
  }
}

extern "C" void kernel_launch(void* const* d_in, const int* in_sizes, int n_in,
                              void* d_out, int out_size, void* d_ws, size_t ws_size,
                              hipStream_t stream) {
  const float* features_v = (const float*)d_in[0];
  const float* features_u = (const float*)d_in[1];
  const int* edge_v = (const int*)d_in[2];
  const int* edge_u = (const int*)d_in[3];
  const float* Wv1 = (const float*)d_in[4];
  const float* bv1 = (const float*)d_in[5];
  const float* av1 = (const float*)d_in[6];
  const float* Wu1 = (const float*)d_in[7];
  const float* bu1 = (const float*)d_in[8];
  const float* au1 = (const float*)d_in[9];
  const float* Wv2 = (const float*)d_in[10];
  const float* bv2 = (const float*)d_in[11];
  const float* av2 = (const float*)d_in[12];
  const float* Wu2 = (const float*)d_in[13];
  const float* bu2 = (const float*)d_in[14];
  const float* au2 = (const float*)d_in[15];
  const float* Wv3 = (const float*)d_in[16];
  const float* bv3 = (const float*)d_in[17];
  const float* Wu3 = (const float*)d_in[18];
  const float* bu3 = (const float*)d_in[19];
  const int ne = in_sizes[2];

  // ---- workspace layout (~107 MB)
  int* cur_v = (int*)d_ws;                       // [NV]
  int* cur_u = cur_v + NVN;                      // [NU]
  int* off_v = cur_u + NUN;                      // [NV+1]
  int* off_u = off_v + NVN + 1;                  // [NU+1]
  unsigned short* csr_v = (unsigned short*)(off_u + NUN + 1);  // [ne]
  unsigned short* csr_u = csr_v + ne;                          // [ne]
  uintptr_t hbase = (((uintptr_t)(csr_u + ne)) + 15) & ~(uintptr_t)15;
  unsigned short* P1b = (unsigned short*)hbase;  // [NV*128] bf16 (mean_v, later Tv)
  unsigned short* P2b = P1b + (size_t)NVN * 128; // [NU*128] bf16 (mean_u, later Tu)
  unsigned short* E1v = P2b + (size_t)NUN * 128; // [NV*256] bf16 ve1 (later Ve3b)
  unsigned short* E1u = E1v + (size_t)NVN * 256; // [NU*256] bf16 ue1 (later Ue3b)
  unsigned short* Wb = E1u + (size_t)NUN * 256;  // 6*32768 bf16
  unsigned short* Fbv = Wb + 6 * 32768;          // [NV*128] bf16 features_v
  unsigned short* Fbu = Fbv + (size_t)NVN * 128; // [NU*128] bf16 features_u
  unsigned short* Ve3b = E1v;  // [NV*128] bf16, reuse after GEMM2
  unsigned short* Ue3b = E1u;  // [NU*128] bf16

  float* out_v = (float*)d_out;              // [NV,256]
  float* out_u = out_v + (size_t)NVN * 256;  // [NU,256]

  const int eg = (ne + 255) / 256;
  const dim3 gg((NVN * 64) / 256, 2);        // one wave per node, 2 sides
  const dim3 gm(1, (NVN + 63) / 64, 2);      // 64 rows/block, 2 sides

  // ---- prep: weights -> bf16 Wt[N][K], features -> bf16, degree count
  hipMemsetAsync(cur_v, 0, (size_t)(NVN + NUN) * 4, stream);
  PrepArgs pa;
  pa.w[0] = {Wv1, Wb + 0 * 32768, 128, 256};
  pa.w[1] = {Wu1, Wb + 1 * 32768, 128, 256};
  pa.w[2] = {Wv2, Wb + 2 * 32768, 256, 128};
  pa.w[3] = {Wu2, Wb + 3 * 32768, 256, 128};
  pa.w[4] = {Wv3, Wb + 4 * 32768, 256, 128};
  pa.w[5] = {Wu3, Wb + 5 * 32768, 256, 128};
  pa.fv = features_v; pa.fu = features_u;
  pa.fbv = Fbv; pa.fbu = Fbu;
  pa.ev = edge_v; pa.eu = edge_u;
  pa.cnt_v = cur_v; pa.cnt_u = cur_u; pa.ne = ne;
  prep_kernel<<<768 + 6250 + eg, 256, 0, stream>>>(pa);
  scan_kernel<<<2, 1024, 0, stream>>>(cur_v, off_v, NVN, cur_u, off_u, NUN);
  fill_kernel<<<eg, 256, 0, stream>>>(edge_v, edge_u, cur_v, cur_u, csr_v, csr_u, ne);

  // ---- stage 1: neighbor means of bf16 features -> bf16
  {
    GSide a{(const unsigned*)Fbu, csr_v, off_v, nullptr, nullptr, nullptr, P1b, 64};
    GSide b{(const unsigned*)Fbv, csr_u, off_u, nullptr, nullptr, nullptr, P2b, 64};
    gatherk<0><<<gg, 256, 0, stream>>>(a, b, NVN);
  }
  // ve1 = prelu(P1b@Wv1+bv1) -> E1v ; ue1 -> E1u   (K=128, N=256)
  {
    GmSide a{P1b, nullptr, Wb + 0 * 32768, bv1, av1, E1v};
    GmSide b{P2b, nullptr, Wb + 1 * 32768, bu1, au1, E1u};
    gemm_mfma<16, 1, 0, 1, 1><<<gm, 256, 0, stream>>>(a, b, 128, 128, 0, 0, 256, NVN);
  }
  // t_v = ve1@Wu2 -> Tv(P1b) ; t_u = ue1@Wv2 -> Tu(P2b)   (K=256, N=128)
  {
    GmSide a{E1v, nullptr, Wb + 3 * 32768, nullptr, nullptr, P1b};
    GmSide b{E1u, nullptr, Wb + 2 * 32768, nullptr, nullptr, P2b};
    gemm_mfma<8, 1, 0, 1, 0><<<gm, 256, 0, stream>>>(a, b, 256, 256, 0, 0, 128, NVN);
  }
  // ---- stage 2: ve2 = prelu(mean_gather(Tu)+bv2) -> out_v[:,0:128]
  {
    GSide a{(const unsigned*)P2b, csr_v, off_v, bv2, av2, nullptr, out_v, 256};
    GSide b{(const unsigned*)P1b, csr_u, off_u, bu2, au2, nullptr, out_u, 256};
    gatherk<1><<<gg, 256, 0, stream>>>(a, b, NVN);
  }
  // ---- stage 3: ve3 = concat(ve2, fv)@Wv3+bv3 -> Ve3b (bf16)
  {
    GmSide a{out_v, Fbv, Wb + 4 * 32768, bv3, nullptr, Ve3b};
    GmSide b{out_u, Fbu, Wb + 5 * 32768, bu3, nullptr, Ue3b};
    gemm_mfma<8, 0, 1, 1, 0><<<gm, 256, 0, stream>>>(a, b, 256, 128, 128, 128, 128, NVN);
  }
  // sv = (gather_sum(Ue3b)+Ve3b)/(deg_v+1) -> out_v[:,128:256]
  {
    GSide a{(const unsigned*)Ue3b, csr_v, off_v, nullptr, nullptr,
            (const unsigned*)Ve3b, out_v + 128, 256};
    GSide b{(const unsigned*)Ve3b, csr_u, off_u, nullptr, nullptr,
            (const unsigned*)Ue3b, out_u + 128, 256};
    gatherk<2><<<gg, 256, 0, stream>>>(a, b, NVN);
  }
}

// Round 5
// 618.171 us; speedup vs baseline: 13.6194x; 1.1408x over previous
//
#include <hip/hip_runtime.h>
#include <stdint.h>

#define NVN 50000
#define NUN 50000
#define NB 49          // buckets of 1024 nodes per side
#define CH 4096        // edges per bucket_scatter block
#define BCAP 24576     // LDS staging capacity (edges) in bucket_build

typedef __attribute__((ext_vector_type(8))) short short8v;
typedef __attribute__((ext_vector_type(8))) unsigned short ushort8v;
typedef __attribute__((ext_vector_type(4))) float float4v;

__device__ __forceinline__ unsigned short f2bf(float f) {
  union { float f; unsigned u; } x; x.f = f;
  unsigned r = x.u + 0x7FFFu + ((x.u >> 16) & 1u);
  return (unsigned short)(r >> 16);
}
__device__ __forceinline__ float bf2f(unsigned short h) {
  union { unsigned u; float f; } x; x.u = ((unsigned)h) << 16;
  return x.f;
}

// ---------------- prep: weight convert+transpose, feature f32->bf16, count
struct WConvEnt { const float* src; unsigned short* dst; int K; int N; };
struct PrepArgs {
  WConvEnt w[6];
  const float* fv; const float* fu;
  unsigned short* fbv; unsigned short* fbu;
  const int* ev; const int* eu;
  int* cnt_v; int* cnt_u; int ne;
};
__global__ __launch_bounds__(256) void prep_kernel(PrepArgs a) {
  int b = blockIdx.x;
  if (b < 768) {  // 6 weights x 128 blocks
    WConvEnt c = a.w[b >> 7];
    int i = (b & 127) * 256 + threadIdx.x;
    int k = i / c.N, n = i - k * c.N;
    c.dst[(size_t)n * c.K + k] = f2bf(c.src[i]);  // Wt[N][K]
    return;
  }
  b -= 768;
  if (b < 6250) {  // features: 3125 blocks per side, 8 elems/thread
    const float* src = (b < 3125) ? a.fv : a.fu;
    unsigned short* dst = (b < 3125) ? a.fbv : a.fbu;
    int bb = (b < 3125) ? b : b - 3125;
    size_t base = ((size_t)bb * 256 + threadIdx.x) * 8;
    float4 x = *(const float4*)(src + base);
    float4 y = *(const float4*)(src + base + 4);
    ushort8v r;
    r[0] = f2bf(x.x); r[1] = f2bf(x.y); r[2] = f2bf(x.z); r[3] = f2bf(x.w);
    r[4] = f2bf(y.x); r[5] = f2bf(y.y); r[6] = f2bf(y.z); r[7] = f2bf(y.w);
    *(ushort8v*)(dst + base) = r;
    return;
  }
  b -= 6250;
  int i = b * 256 + threadIdx.x;
  if (i < a.ne) {
    atomicAdd(&a.cnt_v[a.ev[i]], 1);
    atomicAdd(&a.cnt_u[a.eu[i]], 1);
  }
}

// ------- exclusive scan (wave-shuffle); also emits bucket base cursors
__global__ __launch_bounds__(1024) void scan_kernel(int* __restrict__ cnt_v,
                                                    int* __restrict__ off_v,
                                                    int* __restrict__ bcur_v, int n_v,
                                                    int* __restrict__ cnt_u,
                                                    int* __restrict__ off_u,
                                                    int* __restrict__ bcur_u, int n_u) {
  int* cnt = blockIdx.x ? cnt_u : cnt_v;
  int* off = blockIdx.x ? off_u : off_v;
  int* bcur = blockIdx.x ? bcur_u : bcur_v;
  const int n = blockIdx.x ? n_u : n_v;
  __shared__ int wsum[16];
  __shared__ int carry_s;
  const int tid = threadIdx.x;
  const int lane = tid & 63;
  const int w = tid >> 6;
  if (tid == 0) carry_s = 0;
  __syncthreads();
  for (int base = 0; base < n; base += 1024) {
    int i = base + tid;
    int v = (i < n) ? cnt[i] : 0;
    int x = v;
#pragma unroll
    for (int s = 1; s < 64; s <<= 1) {
      int t = __shfl_up(x, (unsigned)s, 64);
      if (lane >= s) x += t;
    }
    if (lane == 63) wsum[w] = x;
    __syncthreads();
    if (w == 0) {
      int y = (lane < 16) ? wsum[lane] : 0;
#pragma unroll
      for (int s = 1; s < 16; s <<= 1) {
        int t = __shfl_up(y, (unsigned)s, 64);
        if (lane >= s) y += t;
      }
      if (lane < 16) wsum[lane] = y;
    }
    __syncthreads();
    int wbase = (w ? wsum[w - 1] : 0) + carry_s;
    int excl = wbase + x - v;
    if (i < n) {
      off[i] = excl;
      if ((i & 1023) == 0) bcur[i >> 10] = excl;
    }
    __syncthreads();
    if (tid == 1023) carry_s = wbase + x;
    __syncthreads();
  }
  if (tid == 0) off[n] = carry_s;
}

// ---------------- phase A: pack edges into bucket-major staged records
// record = (key&1023)<<16 | payload   (payload < 65536)
__global__ __launch_bounds__(256) void bucket_scatter(
    const int* __restrict__ ev, const int* __restrict__ eu,
    int* __restrict__ bcur_v, int* __restrict__ bcur_u,
    unsigned* __restrict__ stg_v, unsigned* __restrict__ stg_u, int ne) {
  __shared__ int cnt[NB];
  __shared__ int pos[NB];
  __shared__ int gbase[NB];
  __shared__ unsigned rec[CH];
  const int side = blockIdx.y;
  const int* key = side ? eu : ev;
  const int* pay = side ? ev : eu;
  int* bcur = side ? bcur_u : bcur_v;
  unsigned* stg = side ? stg_u : stg_v;
  const int tid = threadIdx.x;
  const int e0 = blockIdx.x * CH;
  const int e1 = min(e0 + CH, ne);
  if (tid < NB) cnt[tid] = 0;
  __syncthreads();
  for (int i = e0 + tid; i < e1; i += 256) atomicAdd(&cnt[key[i] >> 10], 1);
  __syncthreads();
  if (tid < 64) {
    int c = (tid < NB) ? cnt[tid] : 0;
    int x = c;
#pragma unroll
    for (int s = 1; s < 64; s <<= 1) {
      int t = __shfl_up(x, (unsigned)s, 64);
      if (tid >= s) x += t;
    }
    if (tid < NB) pos[tid] = x - c;  // exclusive prefix
  }
  __syncthreads();
  for (int i = e0 + tid; i < e1; i += 256) {
    int k = key[i];
    int b = k >> 10;
    int p = atomicAdd(&pos[b], 1);
    rec[p] = ((unsigned)(k & 1023) << 16) | (unsigned)pay[i];
  }
  __syncthreads();
  if (tid < NB) gbase[tid] = atomicAdd(&bcur[tid], cnt[tid]);
  __syncthreads();
  for (int b = 0; b < NB; ++b) {
    int c = cnt[b];
    int lbase = pos[b] - c;
    int gb = gbase[b];
    for (int i = tid; i < c; i += 256) stg[gb + i] = rec[lbase + i];
  }
}

// ---------------- phase B: per-bucket CSR finalize (one block per bucket)
__global__ __launch_bounds__(256) void bucket_build(
    const int* __restrict__ off_v, const int* __restrict__ off_u,
    const unsigned* __restrict__ stg_v, const unsigned* __restrict__ stg_u,
    unsigned short* __restrict__ csr_v, unsigned short* __restrict__ csr_u,
    int nv, int nu) {
  __shared__ int cur[1024];
  __shared__ unsigned short st[BCAP];
  const int side = blockIdx.y;
  const int* off = side ? off_u : off_v;
  const unsigned* stg = side ? stg_u : stg_v;
  unsigned short* csr = side ? csr_u : csr_v;
  const int n = side ? nu : nv;
  const int nbase = blockIdx.x << 10;
  const int nb = min(1024, n - nbase);
  const int ebase = off[nbase];
  const int cnt = off[nbase + nb] - ebase;
  const int tid = threadIdx.x;
  for (int j = tid; j < nb; j += 256) cur[j] = off[nbase + j] - ebase;
  __syncthreads();
  if (cnt <= BCAP) {
    for (int i = tid; i < cnt; i += 256) {
      unsigned r = stg[ebase + i];
      int p = atomicAdd(&cur[r >> 16], 1);
      st[p] = (unsigned short)(r & 0xFFFFu);
    }
    __syncthreads();
    for (int i = tid; i < cnt; i += 256) csr[ebase + i] = st[i];
  } else {  // safety fallback (not expected for this graph)
    for (int i = tid; i < cnt; i += 256) {
      unsigned r = stg[ebase + i];
      int p = atomicAdd(&cur[r >> 16], 1);
      csr[ebase + p] = (unsigned short)(r & 0xFFFFu);
    }
  }
}

// --------------------------------------------------- gather-aggregate d=128
// One wave per destination row; lane owns 2 columns (one bf16x2 uint).
// Edge indices loaded once coalesced, broadcast via __shfl (v_readlane).
struct GSide {
  const unsigned* src;             // bf16x2 rows, 64 uints/row
  const unsigned short* csr; const int* off;
  const float* bias; const float* slope;
  const unsigned* own;             // bf16x2 rows (mode 2)
  void* dst; int ldo;              // ldo in dst elements
};
template <int MODE>
__global__ __launch_bounds__(256) void gatherk(GSide g0, GSide g1, int n) {
  GSide g = blockIdx.y ? g1 : g0;
  int wid = (int)(((size_t)blockIdx.x * 256 + threadIdx.x) >> 6);
  if (wid >= n) return;
  const int lane = threadIdx.x & 63;
  const int s = g.off[wid], e = g.off[wid + 1];
  const int cnt = e - s;
  float ax = 0.f, ay = 0.f;
  int idx = 0;
  if (lane < cnt) idx = (int)g.csr[s + lane];
  const int m = cnt < 64 ? cnt : 64;
  int j = 0;
  for (; j + 3 < m; j += 4) {
    int r0 = __shfl(idx, j, 64);
    int r1 = __shfl(idx, j + 1, 64);
    int r2 = __shfl(idx, j + 2, 64);
    int r3 = __shfl(idx, j + 3, 64);
    unsigned p0 = g.src[(size_t)r0 * 64 + lane];
    unsigned p1 = g.src[(size_t)r1 * 64 + lane];
    unsigned p2 = g.src[(size_t)r2 * 64 + lane];
    unsigned p3 = g.src[(size_t)r3 * 64 + lane];
    ax += bf2f((unsigned short)p0) + bf2f((unsigned short)p1) +
          bf2f((unsigned short)p2) + bf2f((unsigned short)p3);
    ay += bf2f((unsigned short)(p0 >> 16)) + bf2f((unsigned short)(p1 >> 16)) +
          bf2f((unsigned short)(p2 >> 16)) + bf2f((unsigned short)(p3 >> 16));
  }
  for (; j < m; ++j) {
    int r0 = __shfl(idx, j, 64);
    unsigned p0 = g.src[(size_t)r0 * 64 + lane];
    ax += bf2f((unsigned short)p0);
    ay += bf2f((unsigned short)(p0 >> 16));
  }
  for (int i = s + 64; i < e; ++i) {  // extremely rare (deg > 64)
    int r0 = (int)g.csr[i];
    unsigned p0 = g.src[(size_t)r0 * 64 + lane];
    ax += bf2f((unsigned short)p0);
    ay += bf2f((unsigned short)(p0 >> 16));
  }
  const float deg = (float)cnt;
  if (MODE == 0) {
    float inv = 1.f / fmaxf(deg, 1.f);
    unsigned pv = ((unsigned)f2bf(ay * inv) << 16) | (unsigned)f2bf(ax * inv);
    ((unsigned*)g.dst)[(size_t)wid * g.ldo + lane] = pv;
  } else if (MODE == 1) {
    float inv = 1.f / fmaxf(deg, 1.f);
    float sl = g.slope[0];
    float2 b = *(const float2*)(g.bias + lane * 2);
    float ox = ax * inv + b.x, oy = ay * inv + b.y;
    ox = ox >= 0.f ? ox : ox * sl;
    oy = oy >= 0.f ? oy : oy * sl;
    *(float2*)((float*)g.dst + (size_t)wid * g.ldo + lane * 2) = make_float2(ox, oy);
  } else {
    float inv = 1.f / (deg + 1.f);
    unsigned ow = g.own[(size_t)wid * 64 + lane];
    float ox = (ax + bf2f((unsigned short)ow)) * inv;
    float oy = (ay + bf2f((unsigned short)(ow >> 16))) * inv;
    *(float2*)((float*)g.dst + (size_t)wid * g.ldo + lane * 2) = make_float2(ox, oy);
  }
}

// ---------------------------------------------------------------- MFMA GEMM
// C[M,N] = act(concat(A1,A2) @ W + bias), W pre-transposed bf16 [N][K].
struct GmSide {
  const void* A1; const void* A2;
  const unsigned short* Wt;
  const float* bias; const float* slope;
  void* C;
};

template <int BF>
__device__ __forceinline__ short8v load_a8(const void* A, size_t off) {
  if (BF) {
    return *(const short8v*)((const unsigned short*)A + off);
  } else {
    const float* p = (const float*)A + off;
    float4 x = *(const float4*)p;
    float4 y = *(const float4*)(p + 4);
    short8v r;
    r[0] = (short)f2bf(x.x); r[1] = (short)f2bf(x.y);
    r[2] = (short)f2bf(x.z); r[3] = (short)f2bf(x.w);
    r[4] = (short)f2bf(y.x); r[5] = (short)f2bf(y.y);
    r[6] = (short)f2bf(y.z); r[7] = (short)f2bf(y.w);
    return r;
  }
}

template <int NT, int A1BF, int A2BF, int CBF, int ACT>
__global__ __launch_bounds__(256) void gemm_mfma(GmSide s0, GmSide s1,
                                                 int lda1, int K1, int lda2, int K2,
                                                 int ldc, int M) {
  GmSide s = blockIdx.z ? s1 : s0;
  const int K = K1 + K2;
  const int tid = threadIdx.x;
  const int wv = tid >> 6;
  const int lane = tid & 63;
  const int lc = lane & 15;
  const int khi = lane >> 4;
  const int bm = blockIdx.y * 64;
  const int rowa = bm + wv * 16 + lc;

  float4v acc[NT];
#pragma unroll
  for (int i = 0; i < NT; ++i) acc[i] = (float4v){0.f, 0.f, 0.f, 0.f};

  for (int kb = 0; kb < K; kb += 32) {
    const int kg = kb + khi * 8;
    short8v a = (short8v){0, 0, 0, 0, 0, 0, 0, 0};
    if (rowa < M) {
      if (kg < K1) a = load_a8<A1BF>(s.A1, (size_t)rowa * lda1 + kg);
      else         a = load_a8<A2BF>(s.A2, (size_t)rowa * lda2 + (kg - K1));
    }
#pragma unroll
    for (int fn = 0; fn < NT; ++fn) {
      const short8v b = *(const short8v*)(s.Wt + (size_t)(fn * 16 + lc) * K + kg);
      acc[fn] = __builtin_amdgcn_mfma_f32_16x16x32_bf16(a, b, acc[fn], 0, 0, 0);
    }
  }
  const float sl = ACT ? s.slope[0] : 0.f;
#pragma unroll
  for (int fn = 0; fn < NT; ++fn) {
    const int col = fn * 16 + lc;
    const float bv = s.bias ? s.bias[col] : 0.f;
#pragma unroll
    for (int i = 0; i < 4; ++i) {
      const int row = bm + wv * 16 + khi * 4 + i;
      if (row >= M) continue;
      float v = acc[fn][i] + bv;
      if (ACT && v < 0.f) v *= sl;
      if (CBF) ((unsigned short*)s.C)[(size_t)row * ldc + col] = f2bf(v);
      else     ((float*)s.C)[(size_t)row * ldc + col] = v;
    }
  }
}

extern "C" void kernel_launch(void* const* d_in, const int* in_sizes, int n_in,
                              void* d_out, int out_size, void* d_ws, size_t ws_size,
                              hipStream_t stream) {
  const float* features_v = (const float*)d_in[0];
  const float* features_u = (const float*)d_in[1];
  const int* edge_v = (const int*)d_in[2];
  const int* edge_u = (const int*)d_in[3];
  const float* Wv1 = (const float*)d_in[4];
  const float* bv1 = (const float*)d_in[5];
  const float* av1 = (const float*)d_in[6];
  const float* Wu1 = (const float*)d_in[7];
  const float* bu1 = (const float*)d_in[8];
  const float* au1 = (const float*)d_in[9];
  const float* Wv2 = (const float*)d_in[10];
  const float* bv2 = (const float*)d_in[11];
  const float* av2 = (const float*)d_in[12];
  const float* Wu2 = (const float*)d_in[13];
  const float* bu2 = (const float*)d_in[14];
  const float* au2 = (const float*)d_in[15];
  const float* Wv3 = (const float*)d_in[16];
  const float* bv3 = (const float*)d_in[17];
  const float* Wu3 = (const float*)d_in[18];
  const float* bu3 = (const float*)d_in[19];
  const int ne = in_sizes[2];

  // ---- workspace layout
  int* cnt_v = (int*)d_ws;                       // [NV]
  int* cnt_u = cnt_v + NVN;                      // [NU]
  int* off_v = cnt_u + NUN;                      // [NV+1]
  int* off_u = off_v + NVN + 1;                  // [NU+1]
  int* bcur_v = off_u + NUN + 1;                 // [NB]
  int* bcur_u = bcur_v + NB;                     // [NB]
  unsigned short* csr_v = (unsigned short*)(bcur_u + NB);      // [ne]
  unsigned short* csr_u = csr_v + ne;                          // [ne]
  uintptr_t sbase = (((uintptr_t)(csr_u + ne)) + 15) & ~(uintptr_t)15;
  unsigned* stg_v = (unsigned*)sbase;            // [ne]
  unsigned* stg_u = stg_v + ne;                  // [ne]
  unsigned short* P1b = (unsigned short*)(stg_u + ne);  // [NV*128] bf16
  unsigned short* P2b = P1b + (size_t)NVN * 128; // [NU*128] bf16
  unsigned short* E1v = P2b + (size_t)NUN * 128; // [NV*256] bf16 ve1 (later Ve3b)
  unsigned short* E1u = E1v + (size_t)NVN * 256; // [NU*256] bf16 ue1 (later Ue3b)
  unsigned short* Wb = E1u + (size_t)NUN * 256;  // 6*32768 bf16
  unsigned short* Fbv = Wb + 6 * 32768;          // [NV*128] bf16 features_v
  unsigned short* Fbu = Fbv + (size_t)NVN * 128; // [NU*128] bf16 features_u
  unsigned short* Ve3b = E1v;
  unsigned short* Ue3b = E1u;

  float* out_v = (float*)d_out;              // [NV,256]
  float* out_u = out_v + (size_t)NVN * 256;  // [NU,256]

  const int eg = (ne + 255) / 256;
  const dim3 gg((NVN * 64) / 256, 2);        // one wave per node, 2 sides
  const dim3 gm(1, (NVN + 63) / 64, 2);      // 64 rows/block, 2 sides
  const dim3 gsc((ne + CH - 1) / CH, 2);
  const dim3 gbd(NB, 2);

  // ---- prep: weights -> bf16 Wt[N][K], features -> bf16, degree count
  hipMemsetAsync(cnt_v, 0, (size_t)(NVN + NUN) * 4, stream);
  PrepArgs pa;
  pa.w[0] = {Wv1, Wb + 0 * 32768, 128, 256};
  pa.w[1] = {Wu1, Wb + 1 * 32768, 128, 256};
  pa.w[2] = {Wv2, Wb + 2 * 32768, 256, 128};
  pa.w[3] = {Wu2, Wb + 3 * 32768, 256, 128};
  pa.w[4] = {Wv3, Wb + 4 * 32768, 256, 128};
  pa.w[5] = {Wu3, Wb + 5 * 32768, 256, 128};
  pa.fv = features_v; pa.fu = features_u;
  pa.fbv = Fbv; pa.fbu = Fbu;
  pa.ev = edge_v; pa.eu = edge_u;
  pa.cnt_v = cnt_v; pa.cnt_u = cnt_u; pa.ne = ne;
  prep_kernel<<<768 + 6250 + eg, 256, 0, stream>>>(pa);
  scan_kernel<<<2, 1024, 0, stream>>>(cnt_v, off_v, bcur_v, NVN,
                                      cnt_u, off_u, bcur_u, NUN);
  bucket_scatter<<<gsc, 256, 0, stream>>>(edge_v, edge_u, bcur_v, bcur_u,
                                          stg_v, stg_u, ne);
  bucket_build<<<gbd, 256, 0, stream>>>(off_v, off_u, stg_v, stg_u,
                                        csr_v, csr_u, NVN, NUN);

  // ---- stage 1: neighbor means of bf16 features -> bf16
  {
    GSide a{(const unsigned*)Fbu, csr_v, off_v, nullptr, nullptr, nullptr, P1b, 64};
    GSide b{(const unsigned*)Fbv, csr_u, off_u, nullptr, nullptr, nullptr, P2b, 64};
    gatherk<0><<<gg, 256, 0, stream>>>(a, b, NVN);
  }
  // ve1 = prelu(P1b@Wv1+bv1) -> E1v ; ue1 -> E1u   (K=128, N=256)
  {
    GmSide a{P1b, nullptr, Wb + 0 * 32768, bv1, av1, E1v};
    GmSide b{P2b, nullptr, Wb + 1 * 32768, bu1, au1, E1u};
    gemm_mfma<16, 1, 0, 1, 1><<<gm, 256, 0, stream>>>(a, b, 128, 128, 0, 0, 256, NVN);
  }
  // t_v = ve1@Wu2 -> Tv(P1b) ; t_u = ue1@Wv2 -> Tu(P2b)   (K=256, N=128)
  {
    GmSide a{E1v, nullptr, Wb + 3 * 32768, nullptr, nullptr, P1b};
    GmSide b{E1u, nullptr, Wb + 2 * 32768, nullptr, nullptr, P2b};
    gemm_mfma<8, 1, 0, 1, 0><<<gm, 256, 0, stream>>>(a, b, 256, 256, 0, 0, 128, NVN);
  }
  // ---- stage 2: ve2 = prelu(mean_gather(Tu)+bv2) -> out_v[:,0:128]
  {
    GSide a{(const unsigned*)P2b, csr_v, off_v, bv2, av2, nullptr, out_v, 256};
    GSide b{(const unsigned*)P1b, csr_u, off_u, bu2, au2, nullptr, out_u, 256};
    gatherk<1><<<gg, 256, 0, stream>>>(a, b, NVN);
  }
  // ---- stage 3: ve3 = concat(ve2, fv)@Wv3+bv3 -> Ve3b (bf16)
  {
    GmSide a{out_v, Fbv, Wb + 4 * 32768, bv3, nullptr, Ve3b};
    GmSide b{out_u, Fbu, Wb + 5 * 32768, bu3, nullptr, Ue3b};
    gemm_mfma<8, 0, 1, 1, 0><<<gm, 256, 0, stream>>>(a, b, 256, 128, 128, 128, 128, NVN);
  }
  // sv = (gather_sum(Ue3b)+Ve3b)/(deg_v+1) -> out_v[:,128:256]
  {
    GSide a{(const unsigned*)Ue3b, csr_v, off_v, nullptr, nullptr,
            (const unsigned*)Ve3b, out_v + 128, 256};
    GSide b{(const unsigned*)Ve3b, csr_u, off_u, nullptr, nullptr,
            (const unsigned*)Ue3b, out_u + 128, 256};
    gatherk<2><<<gg, 256, 0, stream>>>(a, b, NVN);
  }
}

// Round 6
// 504.201 us; speedup vs baseline: 16.6979x; 1.2260x over previous
//
#include <hip/hip_runtime.h>
#include <stdint.h>

#define NVN 50000
#define NUN 50000
#define NB 49          // buckets of 1024 nodes per side
#define CH 4096        // edges per bucket_scatter block
#define BCAP 24576     // LDS staging capacity (edges) in bucket_build

typedef __attribute__((ext_vector_type(8))) short short8v;
typedef __attribute__((ext_vector_type(8))) unsigned short ushort8v;
typedef __attribute__((ext_vector_type(4))) float float4v;

__device__ __forceinline__ unsigned short f2bf(float f) {
  union { float f; unsigned u; } x; x.f = f;
  unsigned r = x.u + 0x7FFFu + ((x.u >> 16) & 1u);
  return (unsigned short)(r >> 16);
}
__device__ __forceinline__ float bf2f(unsigned short h) {
  union { unsigned u; float f; } x; x.u = ((unsigned)h) << 16;
  return x.f;
}

// ---------------- prep: weight convert+transpose, feature f32->bf16, count
struct WConvEnt { const float* src; unsigned short* dst; int K; int N; };
struct PrepArgs {
  WConvEnt w[6];
  const float* fv; const float* fu;
  unsigned short* fbv; unsigned short* fbu;
  const int* ev; const int* eu;
  int* cnt_v; int* cnt_u; int ne;
};
__global__ __launch_bounds__(256) void prep_kernel(PrepArgs a) {
  int b = blockIdx.x;
  if (b < 768) {  // 6 weights x 128 blocks
    WConvEnt c = a.w[b >> 7];
    int i = (b & 127) * 256 + threadIdx.x;
    int k = i / c.N, n = i - k * c.N;
    c.dst[(size_t)n * c.K + k] = f2bf(c.src[i]);  // Wt[N][K]
    return;
  }
  b -= 768;
  if (b < 6250) {  // features: 3125 blocks per side, 8 elems/thread
    const float* src = (b < 3125) ? a.fv : a.fu;
    unsigned short* dst = (b < 3125) ? a.fbv : a.fbu;
    int bb = (b < 3125) ? b : b - 3125;
    size_t base = ((size_t)bb * 256 + threadIdx.x) * 8;
    float4 x = *(const float4*)(src + base);
    float4 y = *(const float4*)(src + base + 4);
    ushort8v r;
    r[0] = f2bf(x.x); r[1] = f2bf(x.y); r[2] = f2bf(x.z); r[3] = f2bf(x.w);
    r[4] = f2bf(y.x); r[5] = f2bf(y.y); r[6] = f2bf(y.z); r[7] = f2bf(y.w);
    *(ushort8v*)(dst + base) = r;
    return;
  }
  b -= 6250;
  int i = b * 256 + threadIdx.x;
  if (i < a.ne) {
    atomicAdd(&a.cnt_v[a.ev[i]], 1);
    atomicAdd(&a.cnt_u[a.eu[i]], 1);
  }
}

// ------- exclusive scan (wave-shuffle); also emits bucket base cursors
__global__ __launch_bounds__(1024) void scan_kernel(int* __restrict__ cnt_v,
                                                    int* __restrict__ off_v,
                                                    int* __restrict__ bcur_v, int n_v,
                                                    int* __restrict__ cnt_u,
                                                    int* __restrict__ off_u,
                                                    int* __restrict__ bcur_u, int n_u) {
  int* cnt = blockIdx.x ? cnt_u : cnt_v;
  int* off = blockIdx.x ? off_u : off_v;
  int* bcur = blockIdx.x ? bcur_u : bcur_v;
  const int n = blockIdx.x ? n_u : n_v;
  __shared__ int wsum[16];
  __shared__ int carry_s;
  const int tid = threadIdx.x;
  const int lane = tid & 63;
  const int w = tid >> 6;
  if (tid == 0) carry_s = 0;
  __syncthreads();
  for (int base = 0; base < n; base += 1024) {
    int i = base + tid;
    int v = (i < n) ? cnt[i] : 0;
    int x = v;
#pragma unroll
    for (int s = 1; s < 64; s <<= 1) {
      int t = __shfl_up(x, (unsigned)s, 64);
      if (lane >= s) x += t;
    }
    if (lane == 63) wsum[w] = x;
    __syncthreads();
    if (w == 0) {
      int y = (lane < 16) ? wsum[lane] : 0;
#pragma unroll
      for (int s = 1; s < 16; s <<= 1) {
        int t = __shfl_up(y, (unsigned)s, 64);
        if (lane >= s) y += t;
      }
      if (lane < 16) wsum[lane] = y;
    }
    __syncthreads();
    int wbase = (w ? wsum[w - 1] : 0) + carry_s;
    int excl = wbase + x - v;
    if (i < n) {
      off[i] = excl;
      if ((i & 1023) == 0) bcur[i >> 10] = excl;
    }
    __syncthreads();
    if (tid == 1023) carry_s = wbase + x;
    __syncthreads();
  }
  if (tid == 0) off[n] = carry_s;
}

// ---------------- phase A: pack edges into bucket-major staged records
__global__ __launch_bounds__(256) void bucket_scatter(
    const int* __restrict__ ev, const int* __restrict__ eu,
    int* __restrict__ bcur_v, int* __restrict__ bcur_u,
    unsigned* __restrict__ stg_v, unsigned* __restrict__ stg_u, int ne) {
  __shared__ int cnt[NB];
  __shared__ int pos[NB];
  __shared__ int gbase[NB];
  __shared__ unsigned rec[CH];
  const int side = blockIdx.y;
  const int* key = side ? eu : ev;
  const int* pay = side ? ev : eu;
  int* bcur = side ? bcur_u : bcur_v;
  unsigned* stg = side ? stg_u : stg_v;
  const int tid = threadIdx.x;
  const int e0 = blockIdx.x * CH;
  const int e1 = min(e0 + CH, ne);
  if (tid < NB) cnt[tid] = 0;
  __syncthreads();
  for (int i = e0 + tid; i < e1; i += 256) atomicAdd(&cnt[key[i] >> 10], 1);
  __syncthreads();
  if (tid < 64) {
    int c = (tid < NB) ? cnt[tid] : 0;
    int x = c;
#pragma unroll
    for (int s = 1; s < 64; s <<= 1) {
      int t = __shfl_up(x, (unsigned)s, 64);
      if (tid >= s) x += t;
    }
    if (tid < NB) pos[tid] = x - c;  // exclusive prefix
  }
  __syncthreads();
  for (int i = e0 + tid; i < e1; i += 256) {
    int k = key[i];
    int b = k >> 10;
    int p = atomicAdd(&pos[b], 1);
    rec[p] = ((unsigned)(k & 1023) << 16) | (unsigned)pay[i];
  }
  __syncthreads();
  if (tid < NB) gbase[tid] = atomicAdd(&bcur[tid], cnt[tid]);
  __syncthreads();
  for (int b = 0; b < NB; ++b) {
    int c = cnt[b];
    int lbase = pos[b] - c;
    int gb = gbase[b];
    for (int i = tid; i < c; i += 256) stg[gb + i] = rec[lbase + i];
  }
}

// ---------------- phase B: per-bucket CSR finalize (one block per bucket)
__global__ __launch_bounds__(256) void bucket_build(
    const int* __restrict__ off_v, const int* __restrict__ off_u,
    const unsigned* __restrict__ stg_v, const unsigned* __restrict__ stg_u,
    unsigned short* __restrict__ csr_v, unsigned short* __restrict__ csr_u,
    int nv, int nu) {
  __shared__ int cur[1024];
  __shared__ unsigned short st[BCAP];
  const int side = blockIdx.y;
  const int* off = side ? off_u : off_v;
  const unsigned* stg = side ? stg_u : stg_v;
  unsigned short* csr = side ? csr_u : csr_v;
  const int n = side ? nu : nv;
  const int nbase = blockIdx.x << 10;
  const int nb = min(1024, n - nbase);
  const int ebase = off[nbase];
  const int cnt = off[nbase + nb] - ebase;
  const int tid = threadIdx.x;
  for (int j = tid; j < nb; j += 256) cur[j] = off[nbase + j] - ebase;
  __syncthreads();
  if (cnt <= BCAP) {
    for (int i = tid; i < cnt; i += 256) {
      unsigned r = stg[ebase + i];
      int p = atomicAdd(&cur[r >> 16], 1);
      st[p] = (unsigned short)(r & 0xFFFFu);
    }
    __syncthreads();
    for (int i = tid; i < cnt; i += 256) csr[ebase + i] = st[i];
  } else {
    for (int i = tid; i < cnt; i += 256) {
      unsigned r = stg[ebase + i];
      int p = atomicAdd(&cur[r >> 16], 1);
      csr[ebase + p] = (unsigned short)(r & 0xFFFFu);
    }
  }
}

// --------------------------------------------------- gather-aggregate d=128
struct GSide {
  const unsigned* src;             // bf16x2 rows, 64 uints/row
  const unsigned short* csr; const int* off;
  const float* bias; const float* slope;
  const unsigned* own;             // bf16x2 rows (mode 2)
  void* dst; int ldo;              // ldo in dst elements
};
template <int MODE>
__global__ __launch_bounds__(256) void gatherk(GSide g0, GSide g1, int n) {
  GSide g = blockIdx.y ? g1 : g0;
  int wid = (int)(((size_t)blockIdx.x * 256 + threadIdx.x) >> 6);
  if (wid >= n) return;
  const int lane = threadIdx.x & 63;
  const int s = g.off[wid], e = g.off[wid + 1];
  const int cnt = e - s;
  float ax = 0.f, ay = 0.f;
  int idx = 0;
  if (lane < cnt) idx = (int)g.csr[s + lane];
  const int m = cnt < 64 ? cnt : 64;
  int j = 0;
  for (; j + 3 < m; j += 4) {
    int r0 = __shfl(idx, j, 64);
    int r1 = __shfl(idx, j + 1, 64);
    int r2 = __shfl(idx, j + 2, 64);
    int r3 = __shfl(idx, j + 3, 64);
    unsigned p0 = g.src[(size_t)r0 * 64 + lane];
    unsigned p1 = g.src[(size_t)r1 * 64 + lane];
    unsigned p2 = g.src[(size_t)r2 * 64 + lane];
    unsigned p3 = g.src[(size_t)r3 * 64 + lane];
    ax += bf2f((unsigned short)p0) + bf2f((unsigned short)p1) +
          bf2f((unsigned short)p2) + bf2f((unsigned short)p3);
    ay += bf2f((unsigned short)(p0 >> 16)) + bf2f((unsigned short)(p1 >> 16)) +
          bf2f((unsigned short)(p2 >> 16)) + bf2f((unsigned short)(p3 >> 16));
  }
  for (; j < m; ++j) {
    int r0 = __shfl(idx, j, 64);
    unsigned p0 = g.src[(size_t)r0 * 64 + lane];
    ax += bf2f((unsigned short)p0);
    ay += bf2f((unsigned short)(p0 >> 16));
  }
  for (int i = s + 64; i < e; ++i) {  // rare (deg > 64)
    int r0 = (int)g.csr[i];
    unsigned p0 = g.src[(size_t)r0 * 64 + lane];
    ax += bf2f((unsigned short)p0);
    ay += bf2f((unsigned short)(p0 >> 16));
  }
  const float deg = (float)cnt;
  if (MODE == 0) {
    float inv = 1.f / fmaxf(deg, 1.f);
    unsigned pv = ((unsigned)f2bf(ay * inv) << 16) | (unsigned)f2bf(ax * inv);
    ((unsigned*)g.dst)[(size_t)wid * g.ldo + lane] = pv;
  } else if (MODE == 1) {
    float inv = 1.f / fmaxf(deg, 1.f);
    float sl = g.slope[0];
    float2 b = *(const float2*)(g.bias + lane * 2);
    float ox = ax * inv + b.x, oy = ay * inv + b.y;
    ox = ox >= 0.f ? ox : ox * sl;
    oy = oy >= 0.f ? oy : oy * sl;
    *(float2*)((float*)g.dst + (size_t)wid * g.ldo + lane * 2) = make_float2(ox, oy);
  } else {
    float inv = 1.f / (deg + 1.f);
    unsigned ow = g.own[(size_t)wid * 64 + lane];
    float ox = (ax + bf2f((unsigned short)ow)) * inv;
    float oy = (ay + bf2f((unsigned short)(ow >> 16))) * inv;
    *(float2*)((float*)g.dst + (size_t)wid * g.ldo + lane * 2) = make_float2(ox, oy);
  }
}

// ------------------------------------------- MFMA GEMM, register-resident B
// C[M,N] = act(concat(A1,A2) @ W + bias), W pre-transposed bf16 [N][K].
// 4 waves/block; wave wv owns cols [wv*NF*16, (wv+1)*NF*16).
// Each block streams TILES tiles of 16 rows; B fragments (KB x NF short8v)
// live in registers for the whole kernel; A tile t+1 prefetched during
// tile t's MFMAs.
struct GmSide {
  const void* A1; const void* A2;
  const unsigned short* Wt;
  const float* bias; const float* slope;
  void* C;
};

template <int BF>
__device__ __forceinline__ short8v load_a8(const void* A, size_t off) {
  if (BF) {
    return *(const short8v*)((const unsigned short*)A + off);
  } else {
    const float* p = (const float*)A + off;
    float4 x = *(const float4*)p;
    float4 y = *(const float4*)(p + 4);
    short8v r;
    r[0] = (short)f2bf(x.x); r[1] = (short)f2bf(x.y);
    r[2] = (short)f2bf(x.z); r[3] = (short)f2bf(x.w);
    r[4] = (short)f2bf(y.x); r[5] = (short)f2bf(y.y);
    r[6] = (short)f2bf(y.z); r[7] = (short)f2bf(y.w);
    return r;
  }
}

#define TILES 5  // 16-row tiles per block; 50000 = 625*5*16 exactly

template <int KB1, int KB2, int NF, int A1BF, int A2BF, int CBF, int ACT>
__global__ __launch_bounds__(256) void gemm_reg(GmSide s0, GmSide s1,
                                                int lda1, int lda2,
                                                int ldc, int M) {
  constexpr int KB = KB1 + KB2;
  GmSide s = blockIdx.z ? s1 : s0;
  const int K = KB * 32;
  const int tid = threadIdx.x;
  const int wv = tid >> 6;
  const int lane = tid & 63;
  const int lc = lane & 15;
  const int khi = lane >> 4;
  const int bm = blockIdx.x * (16 * TILES);
  const int colbase = wv * (NF * 16);

  // ---- B fragments: register-resident for the whole kernel
  short8v b[KB][NF];
#pragma unroll
  for (int kb = 0; kb < KB; ++kb)
#pragma unroll
    for (int f = 0; f < NF; ++f)
      b[kb][f] = *(const short8v*)(s.Wt + (size_t)(colbase + f * 16 + lc) * K +
                                   kb * 32 + khi * 8);

  const float sl = ACT ? s.slope[0] : 0.f;
  float bias_f[NF];
#pragma unroll
  for (int f = 0; f < NF; ++f)
    bias_f[f] = s.bias ? s.bias[colbase + f * 16 + lc] : 0.f;

  // ---- prologue: load A for tile 0
  short8v a_cur[KB], a_nxt[KB];
  {
    const int rowa = bm + lc;
#pragma unroll
    for (int kb = 0; kb < KB; ++kb) {
      if (kb < KB1)
        a_cur[kb] = load_a8<A1BF>(s.A1, (size_t)rowa * lda1 + kb * 32 + khi * 8);
      else
        a_cur[kb] = load_a8<A2BF>(s.A2, (size_t)rowa * lda2 + (kb - KB1) * 32 + khi * 8);
    }
  }

  for (int t = 0; t < TILES; ++t) {
    // prefetch next tile's A while current tile computes
    if (t + 1 < TILES) {
      const int rowa = bm + (t + 1) * 16 + lc;
#pragma unroll
      for (int kb = 0; kb < KB; ++kb) {
        if (kb < KB1)
          a_nxt[kb] = load_a8<A1BF>(s.A1, (size_t)rowa * lda1 + kb * 32 + khi * 8);
        else
          a_nxt[kb] = load_a8<A2BF>(s.A2, (size_t)rowa * lda2 + (kb - KB1) * 32 + khi * 8);
      }
    }
    float4v acc[NF];
#pragma unroll
    for (int f = 0; f < NF; ++f) acc[f] = (float4v){0.f, 0.f, 0.f, 0.f};
#pragma unroll
    for (int kb = 0; kb < KB; ++kb)
#pragma unroll
      for (int f = 0; f < NF; ++f)
        acc[f] = __builtin_amdgcn_mfma_f32_16x16x32_bf16(a_cur[kb], b[kb][f],
                                                         acc[f], 0, 0, 0);
    // epilogue for this tile
#pragma unroll
    for (int f = 0; f < NF; ++f) {
      const int col = colbase + f * 16 + lc;
#pragma unroll
      for (int i = 0; i < 4; ++i) {
        const int row = bm + t * 16 + khi * 4 + i;
        float v = acc[f][i] + bias_f[f];
        if (ACT && v < 0.f) v *= sl;
        if (CBF) ((unsigned short*)s.C)[(size_t)row * ldc + col] = f2bf(v);
        else     ((float*)s.C)[(size_t)row * ldc + col] = v;
      }
    }
#pragma unroll
    for (int kb = 0; kb < KB; ++kb) a_cur[kb] = a_nxt[kb];
  }
}

extern "C" void kernel_launch(void* const* d_in, const int* in_sizes, int n_in,
                              void* d_out, int out_size, void* d_ws, size_t ws_size,
                              hipStream_t stream) {
  const float* features_v = (const float*)d_in[0];
  const float* features_u = (const float*)d_in[1];
  const int* edge_v = (const int*)d_in[2];
  const int* edge_u = (const int*)d_in[3];
  const float* Wv1 = (const float*)d_in[4];
  const float* bv1 = (const float*)d_in[5];
  const float* av1 = (const float*)d_in[6];
  const float* Wu1 = (const float*)d_in[7];
  const float* bu1 = (const float*)d_in[8];
  const float* au1 = (const float*)d_in[9];
  const float* Wv2 = (const float*)d_in[10];
  const float* bv2 = (const float*)d_in[11];
  const float* av2 = (const float*)d_in[12];
  const float* Wu2 = (const float*)d_in[13];
  const float* bu2 = (const float*)d_in[14];
  const float* au2 = (const float*)d_in[15];
  const float* Wv3 = (const float*)d_in[16];
  const float* bv3 = (const float*)d_in[17];
  const float* Wu3 = (const float*)d_in[18];
  const float* bu3 = (const float*)d_in[19];
  const int ne = in_sizes[2];

  // ---- workspace layout
  int* cnt_v = (int*)d_ws;                       // [NV]
  int* cnt_u = cnt_v + NVN;                      // [NU]
  int* off_v = cnt_u + NUN;                      // [NV+1]
  int* off_u = off_v + NVN + 1;                  // [NU+1]
  int* bcur_v = off_u + NUN + 1;                 // [NB]
  int* bcur_u = bcur_v + NB;                     // [NB]
  unsigned short* csr_v = (unsigned short*)(bcur_u + NB);      // [ne]
  unsigned short* csr_u = csr_v + ne;                          // [ne]
  uintptr_t sbase = (((uintptr_t)(csr_u + ne)) + 15) & ~(uintptr_t)15;
  unsigned* stg_v = (unsigned*)sbase;            // [ne]
  unsigned* stg_u = stg_v + ne;                  // [ne]
  unsigned short* P1b = (unsigned short*)(stg_u + ne);  // [NV*128] bf16
  unsigned short* P2b = P1b + (size_t)NVN * 128; // [NU*128] bf16
  unsigned short* E1v = P2b + (size_t)NUN * 128; // [NV*256] bf16 ve1 (later Ve3b)
  unsigned short* E1u = E1v + (size_t)NVN * 256; // [NU*256] bf16 ue1 (later Ue3b)
  unsigned short* Wb = E1u + (size_t)NUN * 256;  // 6*32768 bf16
  unsigned short* Fbv = Wb + 6 * 32768;          // [NV*128] bf16 features_v
  unsigned short* Fbu = Fbv + (size_t)NVN * 128; // [NU*128] bf16 features_u
  unsigned short* Ve3b = E1v;
  unsigned short* Ue3b = E1u;

  float* out_v = (float*)d_out;              // [NV,256]
  float* out_u = out_v + (size_t)NVN * 256;  // [NU,256]

  const int eg = (ne + 255) / 256;
  const dim3 gg((NVN * 64) / 256, 2);        // one wave per node, 2 sides
  const dim3 gr(NVN / (16 * TILES), 1, 2);   // 625 blocks, 2 sides
  const dim3 gsc((ne + CH - 1) / CH, 2);
  const dim3 gbd(NB, 2);

  // ---- prep: weights -> bf16 Wt[N][K], features -> bf16, degree count
  hipMemsetAsync(cnt_v, 0, (size_t)(NVN + NUN) * 4, stream);
  PrepArgs pa;
  pa.w[0] = {Wv1, Wb + 0 * 32768, 128, 256};
  pa.w[1] = {Wu1, Wb + 1 * 32768, 128, 256};
  pa.w[2] = {Wv2, Wb + 2 * 32768, 256, 128};
  pa.w[3] = {Wu2, Wb + 3 * 32768, 256, 128};
  pa.w[4] = {Wv3, Wb + 4 * 32768, 256, 128};
  pa.w[5] = {Wu3, Wb + 5 * 32768, 256, 128};
  pa.fv = features_v; pa.fu = features_u;
  pa.fbv = Fbv; pa.fbu = Fbu;
  pa.ev = edge_v; pa.eu = edge_u;
  pa.cnt_v = cnt_v; pa.cnt_u = cnt_u; pa.ne = ne;
  prep_kernel<<<768 + 6250 + eg, 256, 0, stream>>>(pa);
  scan_kernel<<<2, 1024, 0, stream>>>(cnt_v, off_v, bcur_v, NVN,
                                      cnt_u, off_u, bcur_u, NUN);
  bucket_scatter<<<gsc, 256, 0, stream>>>(edge_v, edge_u, bcur_v, bcur_u,
                                          stg_v, stg_u, ne);
  bucket_build<<<gbd, 256, 0, stream>>>(off_v, off_u, stg_v, stg_u,
                                        csr_v, csr_u, NVN, NUN);

  // ---- stage 1: neighbor means of bf16 features -> bf16
  {
    GSide a{(const unsigned*)Fbu, csr_v, off_v, nullptr, nullptr, nullptr, P1b, 64};
    GSide b{(const unsigned*)Fbv, csr_u, off_u, nullptr, nullptr, nullptr, P2b, 64};
    gatherk<0><<<gg, 256, 0, stream>>>(a, b, NVN);
  }
  // ve1 = prelu(P1b@Wv1+bv1) -> E1v ; ue1 -> E1u   (K=128, N=256; NF=4)
  {
    GmSide a{P1b, nullptr, Wb + 0 * 32768, bv1, av1, E1v};
    GmSide b{P2b, nullptr, Wb + 1 * 32768, bu1, au1, E1u};
    gemm_reg<4, 0, 4, 1, 0, 1, 1><<<gr, 256, 0, stream>>>(a, b, 128, 0, 256, NVN);
  }
  // t_v = ve1@Wu2 -> Tv(P1b) ; t_u = ue1@Wv2 -> Tu(P2b)   (K=256, N=128; NF=2)
  {
    GmSide a{E1v, nullptr, Wb + 3 * 32768, nullptr, nullptr, P1b};
    GmSide b{E1u, nullptr, Wb + 2 * 32768, nullptr, nullptr, P2b};
    gemm_reg<8, 0, 2, 1, 0, 1, 0><<<gr, 256, 0, stream>>>(a, b, 256, 0, 128, NVN);
  }
  // ---- stage 2: ve2 = prelu(mean_gather(Tu)+bv2) -> out_v[:,0:128]
  {
    GSide a{(const unsigned*)P2b, csr_v, off_v, bv2, av2, nullptr, out_v, 256};
    GSide b{(const unsigned*)P1b, csr_u, off_u, bu2, au2, nullptr, out_u, 256};
    gatherk<1><<<gg, 256, 0, stream>>>(a, b, NVN);
  }
  // ---- stage 3: ve3 = concat(ve2, fv)@Wv3+bv3 -> Ve3b (bf16)
  {
    GmSide a{out_v, Fbv, Wb + 4 * 32768, bv3, nullptr, Ve3b};
    GmSide b{out_u, Fbu, Wb + 5 * 32768, bu3, nullptr, Ue3b};
    gemm_reg<4, 4, 2, 0, 1, 1, 0><<<gr, 256, 0, stream>>>(a, b, 256, 128, 128, NVN);
  }
  // sv = (gather_sum(Ue3b)+Ve3b)/(deg_v+1) -> out_v[:,128:256]
  {
    GSide a{(const unsigned*)Ue3b, csr_v, off_v, nullptr, nullptr,
            (const unsigned*)Ve3b, out_v + 128, 256};
    GSide b{(const unsigned*)Ve3b, csr_u, off_u, nullptr, nullptr,
            (const unsigned*)Ue3b, out_u + 128, 256};
    gatherk<2><<<gg, 256, 0, stream>>>(a, b, NVN);
  }
}

// Round 7
// 423.964 us; speedup vs baseline: 19.8580x; 1.1893x over previous
//
#include <hip/hip_runtime.h>
#include <stdint.h>

#define NVN 50000
#define NUN 50000
#define NB 49          // buckets of 1024 nodes per side
#define CH 4096        // edges per bucket_scatter block
#define HCH 8192       // edges per histogram block (in prep)
#define BCAP 24576     // LDS staging capacity (edges) in bucket_build

typedef __attribute__((ext_vector_type(8))) short short8v;
typedef __attribute__((ext_vector_type(8))) unsigned short ushort8v;
typedef __attribute__((ext_vector_type(4))) float float4v;

__device__ __forceinline__ unsigned short f2bf(float f) {
  union { float f; unsigned u; } x; x.f = f;
  unsigned r = x.u + 0x7FFFu + ((x.u >> 16) & 1u);
  return (unsigned short)(r >> 16);
}
__device__ __forceinline__ float bf2f(unsigned short h) {
  union { unsigned u; float f; } x; x.u = ((unsigned)h) << 16;
  return x.f;
}

// ---- prep: weight convert+transpose, feature f32->bf16, bucket histogram
struct WConvEnt { const float* src; unsigned short* dst; int K; int N; };
struct PrepArgs {
  WConvEnt w[6];
  const float* fv; const float* fu;
  unsigned short* fbv; unsigned short* fbu;
  const int* ev; const int* eu;
  int* bcnt;      // [2*NB]
  int ne;
};
__global__ __launch_bounds__(256) void prep_kernel(PrepArgs a) {
  __shared__ int h[2 * NB];
  int b = blockIdx.x;
  if (b < 768) {  // 6 weights x 128 blocks
    WConvEnt c = a.w[b >> 7];
    int i = (b & 127) * 256 + threadIdx.x;
    int k = i / c.N, n = i - k * c.N;
    c.dst[(size_t)n * c.K + k] = f2bf(c.src[i]);  // Wt[N][K]
    return;
  }
  b -= 768;
  if (b < 6250) {  // features: 3125 blocks per side, 8 elems/thread
    const float* src = (b < 3125) ? a.fv : a.fu;
    unsigned short* dst = (b < 3125) ? a.fbv : a.fbu;
    int bb = (b < 3125) ? b : b - 3125;
    size_t base = ((size_t)bb * 256 + threadIdx.x) * 8;
    float4 x = *(const float4*)(src + base);
    float4 y = *(const float4*)(src + base + 4);
    ushort8v r;
    r[0] = f2bf(x.x); r[1] = f2bf(x.y); r[2] = f2bf(x.z); r[3] = f2bf(x.w);
    r[4] = f2bf(y.x); r[5] = f2bf(y.y); r[6] = f2bf(y.z); r[7] = f2bf(y.w);
    *(ushort8v*)(dst + base) = r;
    return;
  }
  b -= 6250;  // bucket histogram over an HCH-edge chunk
  const int tid = threadIdx.x;
  for (int j = tid; j < 2 * NB; j += 256) h[j] = 0;
  __syncthreads();
  const int e0 = b * HCH;
  const int e1 = min(e0 + HCH, a.ne);
  for (int i = e0 + tid; i < e1; i += 256) {
    atomicAdd(&h[a.ev[i] >> 10], 1);
    atomicAdd(&h[NB + (a.eu[i] >> 10)], 1);
  }
  __syncthreads();
  for (int j = tid; j < 2 * NB; j += 256)
    if (h[j]) atomicAdd(&a.bcnt[j], h[j]);
}

// ---- tiny scan: 98 bucket counts -> bases (+cursors)
__global__ __launch_bounds__(64) void tiny_scan(const int* __restrict__ bcnt,
                                                int* __restrict__ bbase,
                                                int* __restrict__ bcur) {
  if (threadIdx.x == 0) {
    int acc = 0;
    for (int b = 0; b < NB; ++b) { bbase[b] = acc; bcur[b] = acc; acc += bcnt[b]; }
    bbase[NB] = acc;
    acc = 0;
    for (int b = 0; b < NB; ++b) {
      bbase[NB + 1 + b] = acc; bcur[NB + b] = acc; acc += bcnt[NB + b];
    }
    bbase[2 * NB + 1] = acc;
  }
}

// ---- phase A: pack edges into bucket-major staged records
__global__ __launch_bounds__(256) void bucket_scatter(
    const int* __restrict__ ev, const int* __restrict__ eu,
    int* __restrict__ bcur_v, int* __restrict__ bcur_u,
    unsigned* __restrict__ stg_v, unsigned* __restrict__ stg_u, int ne) {
  __shared__ int cnt[NB];
  __shared__ int pos[NB];
  __shared__ int gbase[NB];
  __shared__ unsigned rec[CH];
  const int side = blockIdx.y;
  const int* key = side ? eu : ev;
  const int* pay = side ? ev : eu;
  int* bcur = side ? bcur_u : bcur_v;
  unsigned* stg = side ? stg_u : stg_v;
  const int tid = threadIdx.x;
  const int e0 = blockIdx.x * CH;
  const int e1 = min(e0 + CH, ne);
  if (tid < NB) cnt[tid] = 0;
  __syncthreads();
  for (int i = e0 + tid; i < e1; i += 256) atomicAdd(&cnt[key[i] >> 10], 1);
  __syncthreads();
  if (tid < 64) {
    int c = (tid < NB) ? cnt[tid] : 0;
    int x = c;
#pragma unroll
    for (int s = 1; s < 64; s <<= 1) {
      int t = __shfl_up(x, (unsigned)s, 64);
      if (tid >= s) x += t;
    }
    if (tid < NB) pos[tid] = x - c;  // exclusive prefix
  }
  __syncthreads();
  for (int i = e0 + tid; i < e1; i += 256) {
    int k = key[i];
    int b = k >> 10;
    int p = atomicAdd(&pos[b], 1);
    rec[p] = ((unsigned)(k & 1023) << 16) | (unsigned)pay[i];
  }
  __syncthreads();
  if (tid < NB) gbase[tid] = atomicAdd(&bcur[tid], cnt[tid]);
  __syncthreads();
  for (int b = 0; b < NB; ++b) {
    int c = cnt[b];
    int lbase = pos[b] - c;
    int gb = gbase[b];
    for (int i = tid; i < c; i += 256) stg[gb + i] = rec[lbase + i];
  }
}

// ---- phase B: per-bucket CSR finalize; also writes per-node off[]
__global__ __launch_bounds__(256) void bucket_build(
    int* __restrict__ off_v, int* __restrict__ off_u,
    const int* __restrict__ bbase,
    const unsigned* __restrict__ stg_v, const unsigned* __restrict__ stg_u,
    unsigned short* __restrict__ csr_v, unsigned short* __restrict__ csr_u,
    int nv, int nu) {
  __shared__ int cur[1024];
  __shared__ int wred[4];
  __shared__ int wbase[4];
  __shared__ unsigned short st[BCAP];
  const int side = blockIdx.y;
  int* off = side ? off_u : off_v;
  const unsigned* stg = side ? stg_u : stg_v;
  unsigned short* csr = side ? csr_u : csr_v;
  const int n = side ? nu : nv;
  const int* bb = bbase + side * (NB + 1);
  const int nbase = blockIdx.x << 10;
  const int nb = min(1024, n - nbase);
  const int ebase = bb[blockIdx.x];
  const int cnt = bb[blockIdx.x + 1] - ebase;
  const int tid = threadIdx.x;
  const int lane = tid & 63;
  const int w = tid >> 6;

  for (int j = tid; j < 1024; j += 256) cur[j] = 0;
  __syncthreads();
  for (int i = tid; i < cnt; i += 256) atomicAdd(&cur[stg[ebase + i] >> 16], 1);
  __syncthreads();
  // exclusive scan of 1024 counts: thread owns 4 consecutive
  const int j0 = tid * 4;
  int c0 = cur[j0], c1 = cur[j0 + 1], c2 = cur[j0 + 2], c3 = cur[j0 + 3];
  int tsum = c0 + c1 + c2 + c3;
  int x = tsum;
#pragma unroll
  for (int s = 1; s < 64; s <<= 1) {
    int t = __shfl_up(x, (unsigned)s, 64);
    if (lane >= s) x += t;
  }
  if (lane == 63) wred[w] = x;
  __syncthreads();
  if (tid == 0) {
    int a = 0;
    for (int k = 0; k < 4; ++k) { wbase[k] = a; a += wred[k]; }
  }
  __syncthreads();
  const int ex = wbase[w] + (x - tsum);
  cur[j0] = ex;
  cur[j0 + 1] = ex + c0;
  cur[j0 + 2] = ex + c0 + c1;
  cur[j0 + 3] = ex + c0 + c1 + c2;
  __syncthreads();
  for (int j = tid; j < nb; j += 256) off[nbase + j] = ebase + cur[j];
  if (nbase + nb == n && tid == 0) off[n] = ebase + cnt;
  __syncthreads();
  if (cnt <= BCAP) {
    for (int i = tid; i < cnt; i += 256) {
      unsigned r = stg[ebase + i];
      int p = atomicAdd(&cur[r >> 16], 1);
      st[p] = (unsigned short)(r & 0xFFFFu);
    }
    __syncthreads();
    for (int i = tid; i < cnt; i += 256) csr[ebase + i] = st[i];
  } else {  // safety fallback
    for (int i = tid; i < cnt; i += 256) {
      unsigned r = stg[ebase + i];
      int p = atomicAdd(&cur[r >> 16], 1);
      csr[ebase + p] = (unsigned short)(r & 0xFFFFu);
    }
  }
}

// --------------------------------------------------- gather-aggregate d=128
struct GSide {
  const unsigned* src;             // bf16x2 rows, 64 uints/row
  const unsigned short* csr; const int* off;
  const float* bias; const float* slope;
  const unsigned* own;             // bf16x2 rows (mode 2)
  void* dst; int ldo;              // ldo in dst elements
};
template <int MODE>
__global__ __launch_bounds__(256) void gatherk(GSide g0, GSide g1, int n) {
  GSide g = blockIdx.y ? g1 : g0;
  int wid = (int)(((size_t)blockIdx.x * 256 + threadIdx.x) >> 6);
  if (wid >= n) return;
  const int lane = threadIdx.x & 63;
  const int s = g.off[wid], e = g.off[wid + 1];
  const int cnt = e - s;
  float ax = 0.f, ay = 0.f;
  int idx = 0;
  if (lane < cnt) idx = (int)g.csr[s + lane];
  const int m = cnt < 64 ? cnt : 64;
  int j = 0;
  for (; j + 3 < m; j += 4) {
    int r0 = __shfl(idx, j, 64);
    int r1 = __shfl(idx, j + 1, 64);
    int r2 = __shfl(idx, j + 2, 64);
    int r3 = __shfl(idx, j + 3, 64);
    unsigned p0 = g.src[(size_t)r0 * 64 + lane];
    unsigned p1 = g.src[(size_t)r1 * 64 + lane];
    unsigned p2 = g.src[(size_t)r2 * 64 + lane];
    unsigned p3 = g.src[(size_t)r3 * 64 + lane];
    ax += bf2f((unsigned short)p0) + bf2f((unsigned short)p1) +
          bf2f((unsigned short)p2) + bf2f((unsigned short)p3);
    ay += bf2f((unsigned short)(p0 >> 16)) + bf2f((unsigned short)(p1 >> 16)) +
          bf2f((unsigned short)(p2 >> 16)) + bf2f((unsigned short)(p3 >> 16));
  }
  for (; j < m; ++j) {
    int r0 = __shfl(idx, j, 64);
    unsigned p0 = g.src[(size_t)r0 * 64 + lane];
    ax += bf2f((unsigned short)p0);
    ay += bf2f((unsigned short)(p0 >> 16));
  }
  for (int i = s + 64; i < e; ++i) {  // rare (deg > 64)
    int r0 = (int)g.csr[i];
    unsigned p0 = g.src[(size_t)r0 * 64 + lane];
    ax += bf2f((unsigned short)p0);
    ay += bf2f((unsigned short)(p0 >> 16));
  }
  const float deg = (float)cnt;
  if (MODE == 0) {
    float inv = 1.f / fmaxf(deg, 1.f);
    unsigned pv = ((unsigned)f2bf(ay * inv) << 16) | (unsigned)f2bf(ax * inv);
    ((unsigned*)g.dst)[(size_t)wid * g.ldo + lane] = pv;
  } else if (MODE == 1) {
    float inv = 1.f / fmaxf(deg, 1.f);
    float sl = g.slope[0];
    float2 b = *(const float2*)(g.bias + lane * 2);
    float ox = ax * inv + b.x, oy = ay * inv + b.y;
    ox = ox >= 0.f ? ox : ox * sl;
    oy = oy >= 0.f ? oy : oy * sl;
    *(float2*)((float*)g.dst + (size_t)wid * g.ldo + lane * 2) = make_float2(ox, oy);
  } else {
    float inv = 1.f / (deg + 1.f);
    unsigned ow = g.own[(size_t)wid * 64 + lane];
    float ox = (ax + bf2f((unsigned short)ow)) * inv;
    float oy = (ay + bf2f((unsigned short)(ow >> 16))) * inv;
    *(float2*)((float*)g.dst + (size_t)wid * g.ldo + lane * 2) = make_float2(ox, oy);
  }
}

// ------------------------------------------- MFMA GEMM, register-resident B
struct GmSide {
  const void* A1; const void* A2;
  const unsigned short* Wt;
  const float* bias; const float* slope;
  void* C;
};

template <int BF>
__device__ __forceinline__ short8v load_a8(const void* A, size_t off) {
  if (BF) {
    return *(const short8v*)((const unsigned short*)A + off);
  } else {
    const float* p = (const float*)A + off;
    float4 x = *(const float4*)p;
    float4 y = *(const float4*)(p + 4);
    short8v r;
    r[0] = (short)f2bf(x.x); r[1] = (short)f2bf(x.y);
    r[2] = (short)f2bf(x.z); r[3] = (short)f2bf(x.w);
    r[4] = (short)f2bf(y.x); r[5] = (short)f2bf(y.y);
    r[6] = (short)f2bf(y.z); r[7] = (short)f2bf(y.w);
    return r;
  }
}

#define TILES 5  // 16-row tiles per block; 50000 = 625*5*16 exactly

template <int KB1, int KB2, int NF, int A1BF, int A2BF, int CBF, int ACT>
__global__ __launch_bounds__(256) void gemm_reg(GmSide s0, GmSide s1,
                                                int lda1, int lda2,
                                                int ldc, int M) {
  constexpr int KB = KB1 + KB2;
  GmSide s = blockIdx.z ? s1 : s0;
  const int K = KB * 32;
  const int tid = threadIdx.x;
  const int wv = tid >> 6;
  const int lane = tid & 63;
  const int lc = lane & 15;
  const int khi = lane >> 4;
  const int bm = blockIdx.x * (16 * TILES);
  const int colbase = wv * (NF * 16);

  short8v b[KB][NF];
#pragma unroll
  for (int kb = 0; kb < KB; ++kb)
#pragma unroll
    for (int f = 0; f < NF; ++f)
      b[kb][f] = *(const short8v*)(s.Wt + (size_t)(colbase + f * 16 + lc) * K +
                                   kb * 32 + khi * 8);

  const float sl = ACT ? s.slope[0] : 0.f;
  float bias_f[NF];
#pragma unroll
  for (int f = 0; f < NF; ++f)
    bias_f[f] = s.bias ? s.bias[colbase + f * 16 + lc] : 0.f;

  short8v a_cur[KB], a_nxt[KB];
  {
    const int rowa = bm + lc;
#pragma unroll
    for (int kb = 0; kb < KB; ++kb) {
      if (kb < KB1)
        a_cur[kb] = load_a8<A1BF>(s.A1, (size_t)rowa * lda1 + kb * 32 + khi * 8);
      else
        a_cur[kb] = load_a8<A2BF>(s.A2, (size_t)rowa * lda2 + (kb - KB1) * 32 + khi * 8);
    }
  }

  for (int t = 0; t < TILES; ++t) {
    if (t + 1 < TILES) {
      const int rowa = bm + (t + 1) * 16 + lc;
#pragma unroll
      for (int kb = 0; kb < KB; ++kb) {
        if (kb < KB1)
          a_nxt[kb] = load_a8<A1BF>(s.A1, (size_t)rowa * lda1 + kb * 32 + khi * 8);
        else
          a_nxt[kb] = load_a8<A2BF>(s.A2, (size_t)rowa * lda2 + (kb - KB1) * 32 + khi * 8);
      }
    }
    float4v acc[NF];
#pragma unroll
    for (int f = 0; f < NF; ++f) acc[f] = (float4v){0.f, 0.f, 0.f, 0.f};
#pragma unroll
    for (int kb = 0; kb < KB; ++kb)
#pragma unroll
      for (int f = 0; f < NF; ++f)
        acc[f] = __builtin_amdgcn_mfma_f32_16x16x32_bf16(a_cur[kb], b[kb][f],
                                                         acc[f], 0, 0, 0);
#pragma unroll
    for (int f = 0; f < NF; ++f) {
      const int col = colbase + f * 16 + lc;
#pragma unroll
      for (int i = 0; i < 4; ++i) {
        const int row = bm + t * 16 + khi * 4 + i;
        float v = acc[f][i] + bias_f[f];
        if (ACT && v < 0.f) v *= sl;
        if (CBF) ((unsigned short*)s.C)[(size_t)row * ldc + col] = f2bf(v);
        else     ((float*)s.C)[(size_t)row * ldc + col] = v;
      }
    }
#pragma unroll
    for (int kb = 0; kb < KB; ++kb) a_cur[kb] = a_nxt[kb];
  }
}

extern "C" void kernel_launch(void* const* d_in, const int* in_sizes, int n_in,
                              void* d_out, int out_size, void* d_ws, size_t ws_size,
                              hipStream_t stream) {
  const float* features_v = (const float*)d_in[0];
  const float* features_u = (const float*)d_in[1];
  const int* edge_v = (const int*)d_in[2];
  const int* edge_u = (const int*)d_in[3];
  const float* Wv1 = (const float*)d_in[4];
  const float* bv1 = (const float*)d_in[5];
  const float* av1 = (const float*)d_in[6];
  const float* Wu1 = (const float*)d_in[7];
  const float* bu1 = (const float*)d_in[8];
  const float* au1 = (const float*)d_in[9];
  const float* Wv2 = (const float*)d_in[10];
  const float* bv2 = (const float*)d_in[11];
  const float* av2 = (const float*)d_in[12];
  const float* Wu2 = (const float*)d_in[13];
  const float* bu2 = (const float*)d_in[14];
  const float* au2 = (const float*)d_in[15];
  const float* Wv3 = (const float*)d_in[16];
  const float* bv3 = (const float*)d_in[17];
  const float* Wu3 = (const float*)d_in[18];
  const float* bu3 = (const float*)d_in[19];
  const int ne = in_sizes[2];

  // ---- workspace layout
  int* bcnt = (int*)d_ws;                        // [2*NB]
  int* bbase = bcnt + 2 * NB;                    // [2*(NB+1)]
  int* bcur = bbase + 2 * (NB + 1);              // [2*NB]
  int* off_v = bcur + 2 * NB;                    // [NV+1]
  int* off_u = off_v + NVN + 1;                  // [NU+1]
  unsigned short* csr_v = (unsigned short*)(off_u + NUN + 1);  // [ne]
  unsigned short* csr_u = csr_v + ne;                          // [ne]
  uintptr_t sbase = (((uintptr_t)(csr_u + ne)) + 15) & ~(uintptr_t)15;
  unsigned* stg_v = (unsigned*)sbase;            // [ne]
  unsigned* stg_u = stg_v + ne;                  // [ne]
  unsigned short* P1b = (unsigned short*)(stg_u + ne);  // [NV*128] bf16
  unsigned short* P2b = P1b + (size_t)NVN * 128; // [NU*128] bf16
  unsigned short* E1v = P2b + (size_t)NUN * 128; // [NV*256] bf16 ve1 (later Ve3b)
  unsigned short* E1u = E1v + (size_t)NVN * 256; // [NU*256] bf16 ue1 (later Ue3b)
  unsigned short* Wb = E1u + (size_t)NUN * 256;  // 6*32768 bf16
  unsigned short* Fbv = Wb + 6 * 32768;          // [NV*128] bf16 features_v
  unsigned short* Fbu = Fbv + (size_t)NVN * 128; // [NU*128] bf16 features_u
  unsigned short* Ve3b = E1v;
  unsigned short* Ue3b = E1u;

  float* out_v = (float*)d_out;              // [NV,256]
  float* out_u = out_v + (size_t)NVN * 256;  // [NU,256]

  const int hb = (ne + HCH - 1) / HCH;
  const dim3 gg((NVN * 64) / 256, 2);        // one wave per node, 2 sides
  const dim3 gr(NVN / (16 * TILES), 1, 2);   // 625 blocks, 2 sides
  const dim3 gsc((ne + CH - 1) / CH, 2);
  const dim3 gbd(NB, 2);

  // ---- prep: weights -> bf16 Wt[N][K], features -> bf16, bucket histogram
  hipMemsetAsync(bcnt, 0, (size_t)(2 * NB) * 4, stream);
  PrepArgs pa;
  pa.w[0] = {Wv1, Wb + 0 * 32768, 128, 256};
  pa.w[1] = {Wu1, Wb + 1 * 32768, 128, 256};
  pa.w[2] = {Wv2, Wb + 2 * 32768, 256, 128};
  pa.w[3] = {Wu2, Wb + 3 * 32768, 256, 128};
  pa.w[4] = {Wv3, Wb + 4 * 32768, 256, 128};
  pa.w[5] = {Wu3, Wb + 5 * 32768, 256, 128};
  pa.fv = features_v; pa.fu = features_u;
  pa.fbv = Fbv; pa.fbu = Fbu;
  pa.ev = edge_v; pa.eu = edge_u;
  pa.bcnt = bcnt; pa.ne = ne;
  prep_kernel<<<768 + 6250 + hb, 256, 0, stream>>>(pa);
  tiny_scan<<<1, 64, 0, stream>>>(bcnt, bbase, bcur);
  bucket_scatter<<<gsc, 256, 0, stream>>>(edge_v, edge_u, bcur, bcur + NB,
                                          stg_v, stg_u, ne);
  bucket_build<<<gbd, 256, 0, stream>>>(off_v, off_u, bbase, stg_v, stg_u,
                                        csr_v, csr_u, NVN, NUN);

  // ---- stage 1: neighbor means of bf16 features -> bf16
  {
    GSide a{(const unsigned*)Fbu, csr_v, off_v, nullptr, nullptr, nullptr, P1b, 64};
    GSide b{(const unsigned*)Fbv, csr_u, off_u, nullptr, nullptr, nullptr, P2b, 64};
    gatherk<0><<<gg, 256, 0, stream>>>(a, b, NVN);
  }
  // ve1 = prelu(P1b@Wv1+bv1) -> E1v ; ue1 -> E1u   (K=128, N=256; NF=4)
  {
    GmSide a{P1b, nullptr, Wb + 0 * 32768, bv1, av1, E1v};
    GmSide b{P2b, nullptr, Wb + 1 * 32768, bu1, au1, E1u};
    gemm_reg<4, 0, 4, 1, 0, 1, 1><<<gr, 256, 0, stream>>>(a, b, 128, 0, 256, NVN);
  }
  // t_v = ve1@Wu2 -> Tv(P1b) ; t_u = ue1@Wv2 -> Tu(P2b)   (K=256, N=128; NF=2)
  {
    GmSide a{E1v, nullptr, Wb + 3 * 32768, nullptr, nullptr, P1b};
    GmSide b{E1u, nullptr, Wb + 2 * 32768, nullptr, nullptr, P2b};
    gemm_reg<8, 0, 2, 1, 0, 1, 0><<<gr, 256, 0, stream>>>(a, b, 256, 0, 128, NVN);
  }
  // ---- stage 2: ve2 = prelu(mean_gather(Tu)+bv2) -> out_v[:,0:128]
  {
    GSide a{(const unsigned*)P2b, csr_v, off_v, bv2, av2, nullptr, out_v, 256};
    GSide b{(const unsigned*)P1b, csr_u, off_u, bu2, au2, nullptr, out_u, 256};
    gatherk<1><<<gg, 256, 0, stream>>>(a, b, NVN);
  }
  // ---- stage 3: ve3 = concat(ve2, fv)@Wv3+bv3 -> Ve3b (bf16)
  {
    GmSide a{out_v, Fbv, Wb + 4 * 32768, bv3, nullptr, Ve3b};
    GmSide b{out_u, Fbu, Wb + 5 * 32768, bu3, nullptr, Ue3b};
    gemm_reg<4, 4, 2, 0, 1, 1, 0><<<gr, 256, 0, stream>>>(a, b, 256, 128, 128, NVN);
  }
  // sv = (gather_sum(Ue3b)+Ve3b)/(deg_v+1) -> out_v[:,128:256]
  {
    GSide a{(const unsigned*)Ue3b, csr_v, off_v, nullptr, nullptr,
            (const unsigned*)Ve3b, out_v + 128, 256};
    GSide b{(const unsigned*)Ve3b, csr_u, off_u, nullptr, nullptr,
            (const unsigned*)Ue3b, out_u + 128, 256};
    gatherk<2><<<gg, 256, 0, stream>>>(a, b, NVN);
  }
}

// Round 8
// 422.829 us; speedup vs baseline: 19.9113x; 1.0027x over previous
//
#include <hip/hip_runtime.h>
#include <stdint.h>

#define NVN 50000
#define NUN 50000
#define NB 49          // buckets of 1024 nodes per side
#define CH 4096        // edges per bucket_scatter block
#define HCH 8192       // edges per histogram block (in prep)
#define BCAP 24576     // LDS staging capacity (edges) in bucket_build

typedef __attribute__((ext_vector_type(8))) short short8v;
typedef __attribute__((ext_vector_type(8))) unsigned short ushort8v;
typedef __attribute__((ext_vector_type(4))) float float4v;

__device__ __forceinline__ unsigned short f2bf(float f) {
  union { float f; unsigned u; } x; x.f = f;
  unsigned r = x.u + 0x7FFFu + ((x.u >> 16) & 1u);
  return (unsigned short)(r >> 16);
}
__device__ __forceinline__ float bf2f(unsigned short h) {
  union { unsigned u; float f; } x; x.u = ((unsigned)h) << 16;
  return x.f;
}

// ---- prep: weight convert+transpose, feature f32->bf16, bucket histogram
struct WConvEnt { const float* src; unsigned short* dst; int K; int N; };
struct PrepArgs {
  WConvEnt w[6];
  const float* fv; const float* fu;
  unsigned short* fbv; unsigned short* fbu;
  const int* ev; const int* eu;
  int* bcnt;      // [2*NB]
  int ne;
};
__global__ __launch_bounds__(256) void prep_kernel(PrepArgs a) {
  __shared__ int h[2 * NB];
  int b = blockIdx.x;
  if (b < 768) {  // 6 weights x 128 blocks
    WConvEnt c = a.w[b >> 7];
    int i = (b & 127) * 256 + threadIdx.x;
    int k = i / c.N, n = i - k * c.N;
    c.dst[(size_t)n * c.K + k] = f2bf(c.src[i]);  // Wt[N][K]
    return;
  }
  b -= 768;
  if (b < 6250) {  // features: 3125 blocks per side, 8 elems/thread
    const float* src = (b < 3125) ? a.fv : a.fu;
    unsigned short* dst = (b < 3125) ? a.fbv : a.fbu;
    int bb = (b < 3125) ? b : b - 3125;
    size_t base = ((size_t)bb * 256 + threadIdx.x) * 8;
    float4 x = *(const float4*)(src + base);
    float4 y = *(const float4*)(src + base + 4);
    ushort8v r;
    r[0] = f2bf(x.x); r[1] = f2bf(x.y); r[2] = f2bf(x.z); r[3] = f2bf(x.w);
    r[4] = f2bf(y.x); r[5] = f2bf(y.y); r[6] = f2bf(y.z); r[7] = f2bf(y.w);
    *(ushort8v*)(dst + base) = r;
    return;
  }
  b -= 6250;  // bucket histogram over an HCH-edge chunk
  const int tid = threadIdx.x;
  for (int j = tid; j < 2 * NB; j += 256) h[j] = 0;
  __syncthreads();
  const int e0 = b * HCH;
  const int e1 = min(e0 + HCH, a.ne);
  for (int i = e0 + tid; i < e1; i += 256) {
    atomicAdd(&h[a.ev[i] >> 10], 1);
    atomicAdd(&h[NB + (a.eu[i] >> 10)], 1);
  }
  __syncthreads();
  for (int j = tid; j < 2 * NB; j += 256)
    if (h[j]) atomicAdd(&a.bcnt[j], h[j]);
}

// ---- tiny scan: 98 bucket counts -> bases (+cursors)
__global__ __launch_bounds__(64) void tiny_scan(const int* __restrict__ bcnt,
                                                int* __restrict__ bbase,
                                                int* __restrict__ bcur) {
  if (threadIdx.x == 0) {
    int acc = 0;
    for (int b = 0; b < NB; ++b) { bbase[b] = acc; bcur[b] = acc; acc += bcnt[b]; }
    bbase[NB] = acc;
    acc = 0;
    for (int b = 0; b < NB; ++b) {
      bbase[NB + 1 + b] = acc; bcur[NB + b] = acc; acc += bcnt[NB + b];
    }
    bbase[2 * NB + 1] = acc;
  }
}

// ---- phase A: pack edges into bucket-major staged records
__global__ __launch_bounds__(256) void bucket_scatter(
    const int* __restrict__ ev, const int* __restrict__ eu,
    int* __restrict__ bcur_v, int* __restrict__ bcur_u,
    unsigned* __restrict__ stg_v, unsigned* __restrict__ stg_u, int ne) {
  __shared__ int cnt[NB];
  __shared__ int pos[NB];
  __shared__ int gbase[NB];
  __shared__ unsigned rec[CH];
  const int side = blockIdx.y;
  const int* key = side ? eu : ev;
  const int* pay = side ? ev : eu;
  int* bcur = side ? bcur_u : bcur_v;
  unsigned* stg = side ? stg_u : stg_v;
  const int tid = threadIdx.x;
  const int e0 = blockIdx.x * CH;
  const int e1 = min(e0 + CH, ne);
  if (tid < NB) cnt[tid] = 0;
  __syncthreads();
  for (int i = e0 + tid; i < e1; i += 256) atomicAdd(&cnt[key[i] >> 10], 1);
  __syncthreads();
  if (tid < 64) {
    int c = (tid < NB) ? cnt[tid] : 0;
    int x = c;
#pragma unroll
    for (int s = 1; s < 64; s <<= 1) {
      int t = __shfl_up(x, (unsigned)s, 64);
      if (tid >= s) x += t;
    }
    if (tid < NB) pos[tid] = x - c;  // exclusive prefix
  }
  __syncthreads();
  for (int i = e0 + tid; i < e1; i += 256) {
    int k = key[i];
    int b = k >> 10;
    int p = atomicAdd(&pos[b], 1);
    rec[p] = ((unsigned)(k & 1023) << 16) | (unsigned)pay[i];
  }
  __syncthreads();
  if (tid < NB) gbase[tid] = atomicAdd(&bcur[tid], cnt[tid]);
  __syncthreads();
  for (int b = 0; b < NB; ++b) {
    int c = cnt[b];
    int lbase = pos[b] - c;
    int gb = gbase[b];
    for (int i = tid; i < c; i += 256) stg[gb + i] = rec[lbase + i];
  }
}

// ---- phase B: per-bucket CSR finalize; also writes per-node off[]
__global__ __launch_bounds__(256) void bucket_build(
    int* __restrict__ off_v, int* __restrict__ off_u,
    const int* __restrict__ bbase,
    const unsigned* __restrict__ stg_v, const unsigned* __restrict__ stg_u,
    unsigned short* __restrict__ csr_v, unsigned short* __restrict__ csr_u,
    int nv, int nu) {
  __shared__ int cur[1024];
  __shared__ int wred[4];
  __shared__ int wbase[4];
  __shared__ unsigned short st[BCAP];
  const int side = blockIdx.y;
  int* off = side ? off_u : off_v;
  const unsigned* stg = side ? stg_u : stg_v;
  unsigned short* csr = side ? csr_u : csr_v;
  const int n = side ? nu : nv;
  const int* bb = bbase + side * (NB + 1);
  const int nbase = blockIdx.x << 10;
  const int nb = min(1024, n - nbase);
  const int ebase = bb[blockIdx.x];
  const int cnt = bb[blockIdx.x + 1] - ebase;
  const int tid = threadIdx.x;
  const int lane = tid & 63;
  const int w = tid >> 6;

  for (int j = tid; j < 1024; j += 256) cur[j] = 0;
  __syncthreads();
  for (int i = tid; i < cnt; i += 256) atomicAdd(&cur[stg[ebase + i] >> 16], 1);
  __syncthreads();
  // exclusive scan of 1024 counts: thread owns 4 consecutive
  const int j0 = tid * 4;
  int c0 = cur[j0], c1 = cur[j0 + 1], c2 = cur[j0 + 2], c3 = cur[j0 + 3];
  int tsum = c0 + c1 + c2 + c3;
  int x = tsum;
#pragma unroll
  for (int s = 1; s < 64; s <<= 1) {
    int t = __shfl_up(x, (unsigned)s, 64);
    if (lane >= s) x += t;
  }
  if (lane == 63) wred[w] = x;
  __syncthreads();
  if (tid == 0) {
    int a = 0;
    for (int k = 0; k < 4; ++k) { wbase[k] = a; a += wred[k]; }
  }
  __syncthreads();
  const int ex = wbase[w] + (x - tsum);
  cur[j0] = ex;
  cur[j0 + 1] = ex + c0;
  cur[j0 + 2] = ex + c0 + c1;
  cur[j0 + 3] = ex + c0 + c1 + c2;
  __syncthreads();
  for (int j = tid; j < nb; j += 256) off[nbase + j] = ebase + cur[j];
  if (nbase + nb == n && tid == 0) off[n] = ebase + cnt;
  __syncthreads();
  if (cnt <= BCAP) {
    for (int i = tid; i < cnt; i += 256) {
      unsigned r = stg[ebase + i];
      int p = atomicAdd(&cur[r >> 16], 1);
      st[p] = (unsigned short)(r & 0xFFFFu);
    }
    __syncthreads();
    for (int i = tid; i < cnt; i += 256) csr[ebase + i] = st[i];
  } else {  // safety fallback
    for (int i = tid; i < cnt; i += 256) {
      unsigned r = stg[ebase + i];
      int p = atomicAdd(&cur[r >> 16], 1);
      csr[ebase + p] = (unsigned short)(r & 0xFFFFu);
    }
  }
}

// --------------------------------------------------- gather-aggregate d=128
// One wave per destination row. 4 row-groups x 16 lanes; each group loads a
// DIFFERENT neighbor row via dwordx4 (16B/lane) => 4 rows per instruction,
// unrolled x2 => 8 rows in flight. Cross-group fold via shfl_xor(16,32).
struct GSide {
  const unsigned* src;             // bf16x2 rows, 64 uints/row
  const unsigned short* csr; const int* off;
  const float* bias; const float* slope;
  const unsigned* own;             // bf16x2 rows (mode 2)
  void* dst; int ldo;              // ldo in dst elements
};

__device__ __forceinline__ void acc8(float* acc, uint4 p) {
  acc[0] += bf2f((unsigned short)p.x);
  acc[1] += bf2f((unsigned short)(p.x >> 16));
  acc[2] += bf2f((unsigned short)p.y);
  acc[3] += bf2f((unsigned short)(p.y >> 16));
  acc[4] += bf2f((unsigned short)p.z);
  acc[5] += bf2f((unsigned short)(p.z >> 16));
  acc[6] += bf2f((unsigned short)p.w);
  acc[7] += bf2f((unsigned short)(p.w >> 16));
}

template <int MODE>
__global__ __launch_bounds__(256) void gatherk(GSide g0, GSide g1, int n) {
  GSide g = blockIdx.y ? g1 : g0;
  int wid = (int)(((size_t)blockIdx.x * 256 + threadIdx.x) >> 6);
  if (wid >= n) return;
  const int lane = threadIdx.x & 63;
  const int grp = lane >> 4;    // row group 0..3
  const int lc = lane & 15;     // 8-col slot
  const int s = g.off[wid], e = g.off[wid + 1];
  const int cnt = e - s;
  float acc[8] = {0.f, 0.f, 0.f, 0.f, 0.f, 0.f, 0.f, 0.f};
  int idx = 0;
  if (lane < cnt) idx = (int)g.csr[s + lane];
  const int m = cnt < 64 ? cnt : 64;
  int j = 0;
  for (; j + 7 < m; j += 8) {
    int r0 = __shfl(idx, j + grp, 64);
    int r1 = __shfl(idx, j + 4 + grp, 64);
    uint4 p0 = *((const uint4*)(g.src + (size_t)r0 * 64) + lc);
    uint4 p1 = *((const uint4*)(g.src + (size_t)r1 * 64) + lc);
    acc8(acc, p0);
    acc8(acc, p1);
  }
  for (; j + 3 < m; j += 4) {
    int r0 = __shfl(idx, j + grp, 64);
    uint4 p0 = *((const uint4*)(g.src + (size_t)r0 * 64) + lc);
    acc8(acc, p0);
  }
  if (j < m) {
    int jj = j + grp;
    int r0 = __shfl(idx, jj < m ? jj : 0, 64);
    if (jj < m) {
      uint4 p0 = *((const uint4*)(g.src + (size_t)r0 * 64) + lc);
      acc8(acc, p0);
    }
  }
  for (int i = s + 64 + grp; i < e; i += 4) {  // rare (deg > 64)
    int r0 = (int)g.csr[i];
    uint4 p0 = *((const uint4*)(g.src + (size_t)r0 * 64) + lc);
    acc8(acc, p0);
  }
  // fold the 4 row-groups
#pragma unroll
  for (int k = 0; k < 8; ++k) {
    acc[k] += __shfl_xor(acc[k], 16, 64);
    acc[k] += __shfl_xor(acc[k], 32, 64);
  }
  if (grp != 0) return;
  const float deg = (float)cnt;
  if (MODE == 0) {
    float inv = 1.f / fmaxf(deg, 1.f);
    uint4 o;
    o.x = ((unsigned)f2bf(acc[1] * inv) << 16) | (unsigned)f2bf(acc[0] * inv);
    o.y = ((unsigned)f2bf(acc[3] * inv) << 16) | (unsigned)f2bf(acc[2] * inv);
    o.z = ((unsigned)f2bf(acc[5] * inv) << 16) | (unsigned)f2bf(acc[4] * inv);
    o.w = ((unsigned)f2bf(acc[7] * inv) << 16) | (unsigned)f2bf(acc[6] * inv);
    *((uint4*)((unsigned*)g.dst + (size_t)wid * g.ldo) + lc) = o;
  } else if (MODE == 1) {
    float inv = 1.f / fmaxf(deg, 1.f);
    float sl = g.slope[0];
    float4 b0 = *(const float4*)(g.bias + lc * 8);
    float4 b1 = *(const float4*)(g.bias + lc * 8 + 4);
    float o[8];
    o[0] = acc[0] * inv + b0.x; o[1] = acc[1] * inv + b0.y;
    o[2] = acc[2] * inv + b0.z; o[3] = acc[3] * inv + b0.w;
    o[4] = acc[4] * inv + b1.x; o[5] = acc[5] * inv + b1.y;
    o[6] = acc[6] * inv + b1.z; o[7] = acc[7] * inv + b1.w;
#pragma unroll
    for (int k = 0; k < 8; ++k) o[k] = o[k] >= 0.f ? o[k] : o[k] * sl;
    float* dp = (float*)g.dst + (size_t)wid * g.ldo + lc * 8;
    *(float4*)dp = make_float4(o[0], o[1], o[2], o[3]);
    *(float4*)(dp + 4) = make_float4(o[4], o[5], o[6], o[7]);
  } else {
    float inv = 1.f / (deg + 1.f);
    uint4 ow = *((const uint4*)(g.own + (size_t)wid * 64) + lc);
    float o[8];
    o[0] = (acc[0] + bf2f((unsigned short)ow.x)) * inv;
    o[1] = (acc[1] + bf2f((unsigned short)(ow.x >> 16))) * inv;
    o[2] = (acc[2] + bf2f((unsigned short)ow.y)) * inv;
    o[3] = (acc[3] + bf2f((unsigned short)(ow.y >> 16))) * inv;
    o[4] = (acc[4] + bf2f((unsigned short)ow.z)) * inv;
    o[5] = (acc[5] + bf2f((unsigned short)(ow.z >> 16))) * inv;
    o[6] = (acc[6] + bf2f((unsigned short)ow.w)) * inv;
    o[7] = (acc[7] + bf2f((unsigned short)(ow.w >> 16))) * inv;
    float* dp = (float*)g.dst + (size_t)wid * g.ldo + lc * 8;
    *(float4*)dp = make_float4(o[0], o[1], o[2], o[3]);
    *(float4*)(dp + 4) = make_float4(o[4], o[5], o[6], o[7]);
  }
}

// ------------------------------------------- MFMA GEMM, register-resident B
struct GmSide {
  const void* A1; const void* A2;
  const unsigned short* Wt;
  const float* bias; const float* slope;
  void* C;
};

template <int BF>
__device__ __forceinline__ short8v load_a8(const void* A, size_t off) {
  if (BF) {
    return *(const short8v*)((const unsigned short*)A + off);
  } else {
    const float* p = (const float*)A + off;
    float4 x = *(const float4*)p;
    float4 y = *(const float4*)(p + 4);
    short8v r;
    r[0] = (short)f2bf(x.x); r[1] = (short)f2bf(x.y);
    r[2] = (short)f2bf(x.z); r[3] = (short)f2bf(x.w);
    r[4] = (short)f2bf(y.x); r[5] = (short)f2bf(y.y);
    r[6] = (short)f2bf(y.z); r[7] = (short)f2bf(y.w);
    return r;
  }
}

#define TILES 5  // 16-row tiles per block; 50000 = 625*5*16 exactly

template <int KB1, int KB2, int NF, int A1BF, int A2BF, int CBF, int ACT>
__global__ __launch_bounds__(256) void gemm_reg(GmSide s0, GmSide s1,
                                                int lda1, int lda2,
                                                int ldc, int M) {
  constexpr int KB = KB1 + KB2;
  GmSide s = blockIdx.z ? s1 : s0;
  const int K = KB * 32;
  const int tid = threadIdx.x;
  const int wv = tid >> 6;
  const int lane = tid & 63;
  const int lc = lane & 15;
  const int khi = lane >> 4;
  const int bm = blockIdx.x * (16 * TILES);
  const int colbase = wv * (NF * 16);

  short8v b[KB][NF];
#pragma unroll
  for (int kb = 0; kb < KB; ++kb)
#pragma unroll
    for (int f = 0; f < NF; ++f)
      b[kb][f] = *(const short8v*)(s.Wt + (size_t)(colbase + f * 16 + lc) * K +
                                   kb * 32 + khi * 8);

  const float sl = ACT ? s.slope[0] : 0.f;
  float bias_f[NF];
#pragma unroll
  for (int f = 0; f < NF; ++f)
    bias_f[f] = s.bias ? s.bias[colbase + f * 16 + lc] : 0.f;

  short8v a_cur[KB], a_nxt[KB];
  {
    const int rowa = bm + lc;
#pragma unroll
    for (int kb = 0; kb < KB; ++kb) {
      if (kb < KB1)
        a_cur[kb] = load_a8<A1BF>(s.A1, (size_t)rowa * lda1 + kb * 32 + khi * 8);
      else
        a_cur[kb] = load_a8<A2BF>(s.A2, (size_t)rowa * lda2 + (kb - KB1) * 32 + khi * 8);
    }
  }

  for (int t = 0; t < TILES; ++t) {
    if (t + 1 < TILES) {
      const int rowa = bm + (t + 1) * 16 + lc;
#pragma unroll
      for (int kb = 0; kb < KB; ++kb) {
        if (kb < KB1)
          a_nxt[kb] = load_a8<A1BF>(s.A1, (size_t)rowa * lda1 + kb * 32 + khi * 8);
        else
          a_nxt[kb] = load_a8<A2BF>(s.A2, (size_t)rowa * lda2 + (kb - KB1) * 32 + khi * 8);
      }
    }
    float4v acc[NF];
#pragma unroll
    for (int f = 0; f < NF; ++f) acc[f] = (float4v){0.f, 0.f, 0.f, 0.f};
#pragma unroll
    for (int kb = 0; kb < KB; ++kb)
#pragma unroll
      for (int f = 0; f < NF; ++f)
        acc[f] = __builtin_amdgcn_mfma_f32_16x16x32_bf16(a_cur[kb], b[kb][f],
                                                         acc[f], 0, 0, 0);
#pragma unroll
    for (int f = 0; f < NF; ++f) {
      const int col = colbase + f * 16 + lc;
#pragma unroll
      for (int i = 0; i < 4; ++i) {
        const int row = bm + t * 16 + khi * 4 + i;
        float v = acc[f][i] + bias_f[f];
        if (ACT && v < 0.f) v *= sl;
        if (CBF) ((unsigned short*)s.C)[(size_t)row * ldc + col] = f2bf(v);
        else     ((float*)s.C)[(size_t)row * ldc + col] = v;
      }
    }
#pragma unroll
    for (int kb = 0; kb < KB; ++kb) a_cur[kb] = a_nxt[kb];
  }
}

extern "C" void kernel_launch(void* const* d_in, const int* in_sizes, int n_in,
                              void* d_out, int out_size, void* d_ws, size_t ws_size,
                              hipStream_t stream) {
  const float* features_v = (const float*)d_in[0];
  const float* features_u = (const float*)d_in[1];
  const int* edge_v = (const int*)d_in[2];
  const int* edge_u = (const int*)d_in[3];
  const float* Wv1 = (const float*)d_in[4];
  const float* bv1 = (const float*)d_in[5];
  const float* av1 = (const float*)d_in[6];
  const float* Wu1 = (const float*)d_in[7];
  const float* bu1 = (const float*)d_in[8];
  const float* au1 = (const float*)d_in[9];
  const float* Wv2 = (const float*)d_in[10];
  const float* bv2 = (const float*)d_in[11];
  const float* av2 = (const float*)d_in[12];
  const float* Wu2 = (const float*)d_in[13];
  const float* bu2 = (const float*)d_in[14];
  const float* au2 = (const float*)d_in[15];
  const float* Wv3 = (const float*)d_in[16];
  const float* bv3 = (const float*)d_in[17];
  const float* Wu3 = (const float*)d_in[18];
  const float* bu3 = (const float*)d_in[19];
  const int ne = in_sizes[2];

  // ---- workspace layout
  int* bcnt = (int*)d_ws;                        // [2*NB]
  int* bbase = bcnt + 2 * NB;                    // [2*(NB+1)]
  int* bcur = bbase + 2 * (NB + 1);              // [2*NB]
  int* off_v = bcur + 2 * NB;                    // [NV+1]
  int* off_u = off_v + NVN + 1;                  // [NU+1]
  unsigned short* csr_v = (unsigned short*)(off_u + NUN + 1);  // [ne]
  unsigned short* csr_u = csr_v + ne;                          // [ne]
  uintptr_t sbase = (((uintptr_t)(csr_u + ne)) + 15) & ~(uintptr_t)15;
  unsigned* stg_v = (unsigned*)sbase;            // [ne]
  unsigned* stg_u = stg_v + ne;                  // [ne]
  unsigned short* P1b = (unsigned short*)(stg_u + ne);  // [NV*128] bf16
  unsigned short* P2b = P1b + (size_t)NVN * 128; // [NU*128] bf16
  unsigned short* E1v = P2b + (size_t)NUN * 128; // [NV*256] bf16 ve1 (later Ve3b)
  unsigned short* E1u = E1v + (size_t)NVN * 256; // [NU*256] bf16 ue1 (later Ue3b)
  unsigned short* Wb = E1u + (size_t)NUN * 256;  // 6*32768 bf16
  unsigned short* Fbv = Wb + 6 * 32768;          // [NV*128] bf16 features_v
  unsigned short* Fbu = Fbv + (size_t)NVN * 128; // [NU*128] bf16 features_u
  unsigned short* Ve3b = E1v;
  unsigned short* Ue3b = E1u;

  float* out_v = (float*)d_out;              // [NV,256]
  float* out_u = out_v + (size_t)NVN * 256;  // [NU,256]

  const int hb = (ne + HCH - 1) / HCH;
  const dim3 gg((NVN * 64) / 256, 2);        // one wave per node, 2 sides
  const dim3 gr(NVN / (16 * TILES), 1, 2);   // 625 blocks, 2 sides
  const dim3 gsc((ne + CH - 1) / CH, 2);
  const dim3 gbd(NB, 2);

  // ---- prep: weights -> bf16 Wt[N][K], features -> bf16, bucket histogram
  hipMemsetAsync(bcnt, 0, (size_t)(2 * NB) * 4, stream);
  PrepArgs pa;
  pa.w[0] = {Wv1, Wb + 0 * 32768, 128, 256};
  pa.w[1] = {Wu1, Wb + 1 * 32768, 128, 256};
  pa.w[2] = {Wv2, Wb + 2 * 32768, 256, 128};
  pa.w[3] = {Wu2, Wb + 3 * 32768, 256, 128};
  pa.w[4] = {Wv3, Wb + 4 * 32768, 256, 128};
  pa.w[5] = {Wu3, Wb + 5 * 32768, 256, 128};
  pa.fv = features_v; pa.fu = features_u;
  pa.fbv = Fbv; pa.fbu = Fbu;
  pa.ev = edge_v; pa.eu = edge_u;
  pa.bcnt = bcnt; pa.ne = ne;
  prep_kernel<<<768 + 6250 + hb, 256, 0, stream>>>(pa);
  tiny_scan<<<1, 64, 0, stream>>>(bcnt, bbase, bcur);
  bucket_scatter<<<gsc, 256, 0, stream>>>(edge_v, edge_u, bcur, bcur + NB,
                                          stg_v, stg_u, ne);
  bucket_build<<<gbd, 256, 0, stream>>>(off_v, off_u, bbase, stg_v, stg_u,
                                        csr_v, csr_u, NVN, NUN);

  // ---- stage 1: neighbor means of bf16 features -> bf16
  {
    GSide a{(const unsigned*)Fbu, csr_v, off_v, nullptr, nullptr, nullptr, P1b, 64};
    GSide b{(const unsigned*)Fbv, csr_u, off_u, nullptr, nullptr, nullptr, P2b, 64};
    gatherk<0><<<gg, 256, 0, stream>>>(a, b, NVN);
  }
  // ve1 = prelu(P1b@Wv1+bv1) -> E1v ; ue1 -> E1u   (K=128, N=256; NF=4)
  {
    GmSide a{P1b, nullptr, Wb + 0 * 32768, bv1, av1, E1v};
    GmSide b{P2b, nullptr, Wb + 1 * 32768, bu1, au1, E1u};
    gemm_reg<4, 0, 4, 1, 0, 1, 1><<<gr, 256, 0, stream>>>(a, b, 128, 0, 256, NVN);
  }
  // t_v = ve1@Wu2 -> Tv(P1b) ; t_u = ue1@Wv2 -> Tu(P2b)   (K=256, N=128; NF=2)
  {
    GmSide a{E1v, nullptr, Wb + 3 * 32768, nullptr, nullptr, P1b};
    GmSide b{E1u, nullptr, Wb + 2 * 32768, nullptr, nullptr, P2b};
    gemm_reg<8, 0, 2, 1, 0, 1, 0><<<gr, 256, 0, stream>>>(a, b, 256, 0, 128, NVN);
  }
  // ---- stage 2: ve2 = prelu(mean_gather(Tu)+bv2) -> out_v[:,0:128]
  {
    GSide a{(const unsigned*)P2b, csr_v, off_v, bv2, av2, nullptr, out_v, 256};
    GSide b{(const unsigned*)P1b, csr_u, off_u, bu2, au2, nullptr, out_u, 256};
    gatherk<1><<<gg, 256, 0, stream>>>(a, b, NVN);
  }
  // ---- stage 3: ve3 = concat(ve2, fv)@Wv3+bv3 -> Ve3b (bf16)
  {
    GmSide a{out_v, Fbv, Wb + 4 * 32768, bv3, nullptr, Ve3b};
    GmSide b{out_u, Fbu, Wb + 5 * 32768, bu3, nullptr, Ue3b};
    gemm_reg<4, 4, 2, 0, 1, 1, 0><<<gr, 256, 0, stream>>>(a, b, 256, 128, 128, NVN);
  }
  // sv = (gather_sum(Ue3b)+Ve3b)/(deg_v+1) -> out_v[:,128:256]
  {
    GSide a{(const unsigned*)Ue3b, csr_v, off_v, nullptr, nullptr,
            (const unsigned*)Ve3b, out_v + 128, 256};
    GSide b{(const unsigned*)Ve3b, csr_u, off_u, nullptr, nullptr,
            (const unsigned*)Ue3b, out_u + 128, 256};
    gatherk<2><<<gg, 256, 0, stream>>>(a, b, NVN);
  }
}

// Round 9
// 392.892 us; speedup vs baseline: 21.4285x; 1.0762x over previous
//
#include <hip/hip_runtime.h>
#include <stdint.h>

#define NVN 50000
#define NUN 50000
#define NB 49          // buckets of 1024 nodes per side
#define CH 4096        // edges per bucket_scatter block
#define HCH 8192       // edges per histogram block (in prep)
#define BCAP 24576     // LDS staging capacity (edges) in bucket_build

typedef __attribute__((ext_vector_type(8))) short short8v;
typedef __attribute__((ext_vector_type(8))) unsigned short ushort8v;
typedef __attribute__((ext_vector_type(4))) float float4v;

__device__ __forceinline__ unsigned short f2bf(float f) {
  union { float f; unsigned u; } x; x.f = f;
  unsigned r = x.u + 0x7FFFu + ((x.u >> 16) & 1u);
  return (unsigned short)(r >> 16);
}
__device__ __forceinline__ float bf2f(unsigned short h) {
  union { unsigned u; float f; } x; x.u = ((unsigned)h) << 16;
  return x.f;
}

// ---- prep: weight convert+transpose, feature f32->bf16, bucket histogram
struct WConvEnt { const float* src; unsigned short* dst; int K; int N; };
struct PrepArgs {
  WConvEnt w[6];
  const float* fv; const float* fu;
  unsigned short* fbv; unsigned short* fbu;
  const int* ev; const int* eu;
  int* bcnt;      // [2*NB]
  int ne;
};
__global__ __launch_bounds__(256) void prep_kernel(PrepArgs a) {
  __shared__ int h[2 * NB];
  int b = blockIdx.x;
  if (b < 768) {  // 6 weights x 128 blocks
    WConvEnt c = a.w[b >> 7];
    int i = (b & 127) * 256 + threadIdx.x;
    int k = i / c.N, n = i - k * c.N;
    c.dst[(size_t)n * c.K + k] = f2bf(c.src[i]);  // Wt[N][K]
    return;
  }
  b -= 768;
  if (b < 6250) {  // features: 3125 blocks per side, 8 elems/thread
    const float* src = (b < 3125) ? a.fv : a.fu;
    unsigned short* dst = (b < 3125) ? a.fbv : a.fbu;
    int bb = (b < 3125) ? b : b - 3125;
    size_t base = ((size_t)bb * 256 + threadIdx.x) * 8;
    float4 x = *(const float4*)(src + base);
    float4 y = *(const float4*)(src + base + 4);
    ushort8v r;
    r[0] = f2bf(x.x); r[1] = f2bf(x.y); r[2] = f2bf(x.z); r[3] = f2bf(x.w);
    r[4] = f2bf(y.x); r[5] = f2bf(y.y); r[6] = f2bf(y.z); r[7] = f2bf(y.w);
    *(ushort8v*)(dst + base) = r;
    return;
  }
  b -= 6250;  // bucket histogram over an HCH-edge chunk
  const int tid = threadIdx.x;
  for (int j = tid; j < 2 * NB; j += 256) h[j] = 0;
  __syncthreads();
  const int e0 = b * HCH;
  const int e1 = min(e0 + HCH, a.ne);
  for (int i = e0 + tid; i < e1; i += 256) {
    atomicAdd(&h[a.ev[i] >> 10], 1);
    atomicAdd(&h[NB + (a.eu[i] >> 10)], 1);
  }
  __syncthreads();
  for (int j = tid; j < 2 * NB; j += 256)
    if (h[j]) atomicAdd(&a.bcnt[j], h[j]);
}

// ---- phase A: pack edges into bucket-major staged records.
// Bucket bases derived in-block from bcnt scan; bcur are RELATIVE cursors.
__global__ __launch_bounds__(256) void bucket_scatter(
    const int* __restrict__ ev, const int* __restrict__ eu,
    const int* __restrict__ bcnt, int* __restrict__ bcur,
    unsigned* __restrict__ stg_v, unsigned* __restrict__ stg_u, int ne) {
  __shared__ int cnt[NB];
  __shared__ int pos[NB];
  __shared__ int gbase[NB];
  __shared__ int bb_s[NB];
  __shared__ unsigned rec[CH];
  const int side = blockIdx.y;
  const int* key = side ? eu : ev;
  const int* pay = side ? ev : eu;
  unsigned* stg = side ? stg_u : stg_v;
  const int tid = threadIdx.x;
  const int e0 = blockIdx.x * CH;
  const int e1 = min(e0 + CH, ne);
  if (tid < NB) cnt[tid] = 0;
  __syncthreads();
  if (tid >= 64 && tid < 128) {  // wave 1: scan bucket counts -> bases
    int t = tid - 64;
    int c = (t < NB) ? bcnt[side * NB + t] : 0;
    int x = c;
#pragma unroll
    for (int s = 1; s < 64; s <<= 1) {
      int tt = __shfl_up(x, (unsigned)s, 64);
      if (t >= s) x += tt;
    }
    if (t < NB) bb_s[t] = x - c;
  }
  for (int i = e0 + tid; i < e1; i += 256) atomicAdd(&cnt[key[i] >> 10], 1);
  __syncthreads();
  if (tid < 64) {
    int c = (tid < NB) ? cnt[tid] : 0;
    int x = c;
#pragma unroll
    for (int s = 1; s < 64; s <<= 1) {
      int t = __shfl_up(x, (unsigned)s, 64);
      if (tid >= s) x += t;
    }
    if (tid < NB) pos[tid] = x - c;  // exclusive prefix
  }
  __syncthreads();
  for (int i = e0 + tid; i < e1; i += 256) {
    int k = key[i];
    int b = k >> 10;
    int p = atomicAdd(&pos[b], 1);
    rec[p] = ((unsigned)(k & 1023) << 16) | (unsigned)pay[i];
  }
  __syncthreads();
  if (tid < NB)
    gbase[tid] = bb_s[tid] + atomicAdd(&bcur[side * NB + tid], cnt[tid]);
  __syncthreads();
  for (int b = 0; b < NB; ++b) {
    int c = cnt[b];
    int lbase = pos[b] - c;
    int gb = gbase[b];
    for (int i = tid; i < c; i += 256) stg[gb + i] = rec[lbase + i];
  }
}

// ---- phase B: per-bucket CSR finalize; also writes per-node off[]
__global__ __launch_bounds__(256) void bucket_build(
    int* __restrict__ off_v, int* __restrict__ off_u,
    const int* __restrict__ bcnt,
    const unsigned* __restrict__ stg_v, const unsigned* __restrict__ stg_u,
    unsigned short* __restrict__ csr_v, unsigned short* __restrict__ csr_u,
    int nv, int nu) {
  __shared__ int cur[1024];
  __shared__ int wred[4];
  __shared__ int wbase[4];
  __shared__ int bb_s[NB + 1];
  __shared__ unsigned short st[BCAP];
  const int side = blockIdx.y;
  int* off = side ? off_u : off_v;
  const unsigned* stg = side ? stg_u : stg_v;
  unsigned short* csr = side ? csr_u : csr_v;
  const int n = side ? nu : nv;
  const int tid = threadIdx.x;
  const int lane = tid & 63;
  const int w = tid >> 6;
  if (tid < 64) {  // scan bucket counts -> bases
    int c = (tid < NB) ? bcnt[side * NB + tid] : 0;
    int x = c;
#pragma unroll
    for (int s = 1; s < 64; s <<= 1) {
      int t = __shfl_up(x, (unsigned)s, 64);
      if (tid >= s) x += t;
    }
    if (tid <= NB) bb_s[tid] = x - c;  // bb_s[NB] = total (c=0 there)
  }
  for (int j = tid; j < 1024; j += 256) cur[j] = 0;
  __syncthreads();
  const int nbase = blockIdx.x << 10;
  const int nb = min(1024, n - nbase);
  const int ebase = bb_s[blockIdx.x];
  const int cnt = bb_s[blockIdx.x + 1] - ebase;
  for (int i = tid; i < cnt; i += 256) atomicAdd(&cur[stg[ebase + i] >> 16], 1);
  __syncthreads();
  // exclusive scan of 1024 counts: thread owns 4 consecutive
  const int j0 = tid * 4;
  int c0 = cur[j0], c1 = cur[j0 + 1], c2 = cur[j0 + 2], c3 = cur[j0 + 3];
  int tsum = c0 + c1 + c2 + c3;
  int x = tsum;
#pragma unroll
  for (int s = 1; s < 64; s <<= 1) {
    int t = __shfl_up(x, (unsigned)s, 64);
    if (lane >= s) x += t;
  }
  if (lane == 63) wred[w] = x;
  __syncthreads();
  if (tid == 0) {
    int a = 0;
    for (int k = 0; k < 4; ++k) { wbase[k] = a; a += wred[k]; }
  }
  __syncthreads();
  const int ex = wbase[w] + (x - tsum);
  cur[j0] = ex;
  cur[j0 + 1] = ex + c0;
  cur[j0 + 2] = ex + c0 + c1;
  cur[j0 + 3] = ex + c0 + c1 + c2;
  __syncthreads();
  for (int j = tid; j < nb; j += 256) off[nbase + j] = ebase + cur[j];
  if (nbase + nb == n && tid == 0) off[n] = ebase + cnt;
  __syncthreads();
  if (cnt <= BCAP) {
    for (int i = tid; i < cnt; i += 256) {
      unsigned r = stg[ebase + i];
      int p = atomicAdd(&cur[r >> 16], 1);
      st[p] = (unsigned short)(r & 0xFFFFu);
    }
    __syncthreads();
    for (int i = tid; i < cnt; i += 256) csr[ebase + i] = st[i];
  } else {  // safety fallback
    for (int i = tid; i < cnt; i += 256) {
      unsigned r = stg[ebase + i];
      int p = atomicAdd(&cur[r >> 16], 1);
      csr[ebase + p] = (unsigned short)(r & 0xFFFFu);
    }
  }
}

// --------------------------------------------------- gather-aggregate d=128
// One wave per destination row. 4 row-groups x 16 lanes; each group loads a
// DIFFERENT neighbor row via dwordx4 => 4 rows/instruction, unrolled x2.
struct GSide {
  const unsigned* src;             // bf16x2 rows, 64 uints/row
  const unsigned short* csr; const int* off;
  const float* bias; const float* slope;
  const unsigned* own;             // bf16x2 rows (mode 2)
  void* dst; int ldo;              // ldo in dst elements
};

__device__ __forceinline__ void acc8(float* acc, uint4 p) {
  acc[0] += bf2f((unsigned short)p.x);
  acc[1] += bf2f((unsigned short)(p.x >> 16));
  acc[2] += bf2f((unsigned short)p.y);
  acc[3] += bf2f((unsigned short)(p.y >> 16));
  acc[4] += bf2f((unsigned short)p.z);
  acc[5] += bf2f((unsigned short)(p.z >> 16));
  acc[6] += bf2f((unsigned short)p.w);
  acc[7] += bf2f((unsigned short)(p.w >> 16));
}

template <int MODE>
__global__ __launch_bounds__(256) void gatherk(GSide g0, GSide g1, int n) {
  GSide g = blockIdx.y ? g1 : g0;
  int wid = (int)(((size_t)blockIdx.x * 256 + threadIdx.x) >> 6);
  if (wid >= n) return;
  const int lane = threadIdx.x & 63;
  const int grp = lane >> 4;    // row group 0..3
  const int lc = lane & 15;     // 8-col slot
  const int s = g.off[wid], e = g.off[wid + 1];
  const int cnt = e - s;
  float acc[8] = {0.f, 0.f, 0.f, 0.f, 0.f, 0.f, 0.f, 0.f};
  int idx = 0;
  if (lane < cnt) idx = (int)g.csr[s + lane];
  const int m = cnt < 64 ? cnt : 64;
  int j = 0;
  for (; j + 7 < m; j += 8) {
    int r0 = __shfl(idx, j + grp, 64);
    int r1 = __shfl(idx, j + 4 + grp, 64);
    uint4 p0 = *((const uint4*)(g.src + (size_t)r0 * 64) + lc);
    uint4 p1 = *((const uint4*)(g.src + (size_t)r1 * 64) + lc);
    acc8(acc, p0);
    acc8(acc, p1);
  }
  for (; j + 3 < m; j += 4) {
    int r0 = __shfl(idx, j + grp, 64);
    uint4 p0 = *((const uint4*)(g.src + (size_t)r0 * 64) + lc);
    acc8(acc, p0);
  }
  if (j < m) {
    int jj = j + grp;
    int r0 = __shfl(idx, jj < m ? jj : 0, 64);
    if (jj < m) {
      uint4 p0 = *((const uint4*)(g.src + (size_t)r0 * 64) + lc);
      acc8(acc, p0);
    }
  }
  for (int i = s + 64 + grp; i < e; i += 4) {  // rare (deg > 64)
    int r0 = (int)g.csr[i];
    uint4 p0 = *((const uint4*)(g.src + (size_t)r0 * 64) + lc);
    acc8(acc, p0);
  }
  // fold the 4 row-groups
#pragma unroll
  for (int k = 0; k < 8; ++k) {
    acc[k] += __shfl_xor(acc[k], 16, 64);
    acc[k] += __shfl_xor(acc[k], 32, 64);
  }
  if (grp != 0) return;
  const float deg = (float)cnt;
  if (MODE == 0) {
    float inv = 1.f / fmaxf(deg, 1.f);
    uint4 o;
    o.x = ((unsigned)f2bf(acc[1] * inv) << 16) | (unsigned)f2bf(acc[0] * inv);
    o.y = ((unsigned)f2bf(acc[3] * inv) << 16) | (unsigned)f2bf(acc[2] * inv);
    o.z = ((unsigned)f2bf(acc[5] * inv) << 16) | (unsigned)f2bf(acc[4] * inv);
    o.w = ((unsigned)f2bf(acc[7] * inv) << 16) | (unsigned)f2bf(acc[6] * inv);
    *((uint4*)((unsigned*)g.dst + (size_t)wid * g.ldo) + lc) = o;
  } else if (MODE == 1) {
    float inv = 1.f / fmaxf(deg, 1.f);
    float sl = g.slope[0];
    float4 b0 = *(const float4*)(g.bias + lc * 8);
    float4 b1 = *(const float4*)(g.bias + lc * 8 + 4);
    float o[8];
    o[0] = acc[0] * inv + b0.x; o[1] = acc[1] * inv + b0.y;
    o[2] = acc[2] * inv + b0.z; o[3] = acc[3] * inv + b0.w;
    o[4] = acc[4] * inv + b1.x; o[5] = acc[5] * inv + b1.y;
    o[6] = acc[6] * inv + b1.z; o[7] = acc[7] * inv + b1.w;
#pragma unroll
    for (int k = 0; k < 8; ++k) o[k] = o[k] >= 0.f ? o[k] : o[k] * sl;
    float* dp = (float*)g.dst + (size_t)wid * g.ldo + lc * 8;
    *(float4*)dp = make_float4(o[0], o[1], o[2], o[3]);
    *(float4*)(dp + 4) = make_float4(o[4], o[5], o[6], o[7]);
  } else {
    float inv = 1.f / (deg + 1.f);
    uint4 ow = *((const uint4*)(g.own + (size_t)wid * 64) + lc);
    float o[8];
    o[0] = (acc[0] + bf2f((unsigned short)ow.x)) * inv;
    o[1] = (acc[1] + bf2f((unsigned short)(ow.x >> 16))) * inv;
    o[2] = (acc[2] + bf2f((unsigned short)ow.y)) * inv;
    o[3] = (acc[3] + bf2f((unsigned short)(ow.y >> 16))) * inv;
    o[4] = (acc[4] + bf2f((unsigned short)ow.z)) * inv;
    o[5] = (acc[5] + bf2f((unsigned short)(ow.z >> 16))) * inv;
    o[6] = (acc[6] + bf2f((unsigned short)ow.w)) * inv;
    o[7] = (acc[7] + bf2f((unsigned short)(ow.w >> 16))) * inv;
    float* dp = (float*)g.dst + (size_t)wid * g.ldo + lc * 8;
    *(float4*)dp = make_float4(o[0], o[1], o[2], o[3]);
    *(float4*)(dp + 4) = make_float4(o[4], o[5], o[6], o[7]);
  }
}

// -------------------- fused GEMM1+GEMM2: T = prelu(A@W1+b1) @ W2
// A [M][128] bf16; W1t [256][128]; W2t [128][256]; T [M][128] bf16.
// Block = 64 rows, 4 waves. Phase 1: wave wv computes cols wv*64..+63 of
// e1 for all 64 rows -> bias+prelu -> LDS (pad 8 => 2-way bank, free).
// Phase 2: A-frags from LDS, cols wv*32..+31 of T.
struct Gm12Side {
  const unsigned short* A;
  const unsigned short* Wt1;
  const float* bias1; const float* slope1;
  const unsigned short* Wt2;
  unsigned short* T;
};

__global__ __launch_bounds__(256) void gemm12(Gm12Side s0, Gm12Side s1, int M) {
  __shared__ unsigned short e1[64][264];  // pad 8
  const Gm12Side s = blockIdx.z ? s1 : s0;
  const int tid = threadIdx.x;
  const int wv = tid >> 6;
  const int lane = tid & 63;
  const int lc = lane & 15;
  const int khi = lane >> 4;
  const int bm = blockIdx.x * 64;

  // phase 1
  short8v b1[4][4];
#pragma unroll
  for (int kb = 0; kb < 4; ++kb)
#pragma unroll
    for (int f = 0; f < 4; ++f)
      b1[kb][f] = *(const short8v*)(s.Wt1 + (size_t)(wv * 64 + f * 16 + lc) * 128 +
                                    kb * 32 + khi * 8);
  short8v a[4][4];
#pragma unroll
  for (int rt = 0; rt < 4; ++rt) {
    const int row = bm + rt * 16 + lc;
#pragma unroll
    for (int kb = 0; kb < 4; ++kb) {
      if (row < M)
        a[rt][kb] = *(const short8v*)(s.A + (size_t)row * 128 + kb * 32 + khi * 8);
      else
        a[rt][kb] = (short8v){0, 0, 0, 0, 0, 0, 0, 0};
    }
  }
  float4v acc[4][4];
#pragma unroll
  for (int rt = 0; rt < 4; ++rt)
#pragma unroll
    for (int f = 0; f < 4; ++f) acc[rt][f] = (float4v){0.f, 0.f, 0.f, 0.f};
#pragma unroll
  for (int kb = 0; kb < 4; ++kb)
#pragma unroll
    for (int rt = 0; rt < 4; ++rt)
#pragma unroll
      for (int f = 0; f < 4; ++f)
        acc[rt][f] = __builtin_amdgcn_mfma_f32_16x16x32_bf16(a[rt][kb], b1[kb][f],
                                                             acc[rt][f], 0, 0, 0);
  const float sl = s.slope1[0];
#pragma unroll
  for (int f = 0; f < 4; ++f) {
    const int col = wv * 64 + f * 16 + lc;
    const float bv = s.bias1[col];
#pragma unroll
    for (int rt = 0; rt < 4; ++rt)
#pragma unroll
      for (int i = 0; i < 4; ++i) {
        float v = acc[rt][f][i] + bv;
        if (v < 0.f) v *= sl;
        e1[rt * 16 + khi * 4 + i][col] = f2bf(v);
      }
  }
  __syncthreads();

  // phase 2
  short8v b2[8][2];
#pragma unroll
  for (int kb = 0; kb < 8; ++kb)
#pragma unroll
    for (int f = 0; f < 2; ++f)
      b2[kb][f] = *(const short8v*)(s.Wt2 + (size_t)(wv * 32 + f * 16 + lc) * 256 +
                                    kb * 32 + khi * 8);
  float4v acc2[4][2];
#pragma unroll
  for (int rt = 0; rt < 4; ++rt)
#pragma unroll
    for (int f = 0; f < 2; ++f) acc2[rt][f] = (float4v){0.f, 0.f, 0.f, 0.f};
#pragma unroll
  for (int kb = 0; kb < 8; ++kb) {
    short8v a2[4];
#pragma unroll
    for (int rt = 0; rt < 4; ++rt)
      a2[rt] = *(const short8v*)(&e1[rt * 16 + lc][kb * 32 + khi * 8]);
#pragma unroll
    for (int rt = 0; rt < 4; ++rt)
#pragma unroll
      for (int f = 0; f < 2; ++f)
        acc2[rt][f] = __builtin_amdgcn_mfma_f32_16x16x32_bf16(a2[rt], b2[kb][f],
                                                              acc2[rt][f], 0, 0, 0);
  }
#pragma unroll
  for (int f = 0; f < 2; ++f) {
    const int col = wv * 32 + f * 16 + lc;
#pragma unroll
    for (int rt = 0; rt < 4; ++rt)
#pragma unroll
      for (int i = 0; i < 4; ++i) {
        const int row = bm + rt * 16 + khi * 4 + i;
        if (row < M) s.T[(size_t)row * 128 + col] = f2bf(acc2[rt][f][i]);
      }
  }
}

// ------------------------------------------- MFMA GEMM, register-resident B
struct GmSide {
  const void* A1; const void* A2;
  const unsigned short* Wt;
  const float* bias; const float* slope;
  void* C;
};

template <int BF>
__device__ __forceinline__ short8v load_a8(const void* A, size_t off) {
  if (BF) {
    return *(const short8v*)((const unsigned short*)A + off);
  } else {
    const float* p = (const float*)A + off;
    float4 x = *(const float4*)p;
    float4 y = *(const float4*)(p + 4);
    short8v r;
    r[0] = (short)f2bf(x.x); r[1] = (short)f2bf(x.y);
    r[2] = (short)f2bf(x.z); r[3] = (short)f2bf(x.w);
    r[4] = (short)f2bf(y.x); r[5] = (short)f2bf(y.y);
    r[6] = (short)f2bf(y.z); r[7] = (short)f2bf(y.w);
    return r;
  }
}

#define TILES 5  // 16-row tiles per block; 50000 = 625*5*16 exactly

template <int KB1, int KB2, int NF, int A1BF, int A2BF, int CBF, int ACT>
__global__ __launch_bounds__(256) void gemm_reg(GmSide s0, GmSide s1,
                                                int lda1, int lda2,
                                                int ldc, int M) {
  constexpr int KB = KB1 + KB2;
  GmSide s = blockIdx.z ? s1 : s0;
  const int K = KB * 32;
  const int tid = threadIdx.x;
  const int wv = tid >> 6;
  const int lane = tid & 63;
  const int lc = lane & 15;
  const int khi = lane >> 4;
  const int bm = blockIdx.x * (16 * TILES);
  const int colbase = wv * (NF * 16);

  short8v b[KB][NF];
#pragma unroll
  for (int kb = 0; kb < KB; ++kb)
#pragma unroll
    for (int f = 0; f < NF; ++f)
      b[kb][f] = *(const short8v*)(s.Wt + (size_t)(colbase + f * 16 + lc) * K +
                                   kb * 32 + khi * 8);

  const float sl = ACT ? s.slope[0] : 0.f;
  float bias_f[NF];
#pragma unroll
  for (int f = 0; f < NF; ++f)
    bias_f[f] = s.bias ? s.bias[colbase + f * 16 + lc] : 0.f;

  short8v a_cur[KB], a_nxt[KB];
  {
    const int rowa = bm + lc;
#pragma unroll
    for (int kb = 0; kb < KB; ++kb) {
      if (kb < KB1)
        a_cur[kb] = load_a8<A1BF>(s.A1, (size_t)rowa * lda1 + kb * 32 + khi * 8);
      else
        a_cur[kb] = load_a8<A2BF>(s.A2, (size_t)rowa * lda2 + (kb - KB1) * 32 + khi * 8);
    }
  }

  for (int t = 0; t < TILES; ++t) {
    if (t + 1 < TILES) {
      const int rowa = bm + (t + 1) * 16 + lc;
#pragma unroll
      for (int kb = 0; kb < KB; ++kb) {
        if (kb < KB1)
          a_nxt[kb] = load_a8<A1BF>(s.A1, (size_t)rowa * lda1 + kb * 32 + khi * 8);
        else
          a_nxt[kb] = load_a8<A2BF>(s.A2, (size_t)rowa * lda2 + (kb - KB1) * 32 + khi * 8);
      }
    }
    float4v acc[NF];
#pragma unroll
    for (int f = 0; f < NF; ++f) acc[f] = (float4v){0.f, 0.f, 0.f, 0.f};
#pragma unroll
    for (int kb = 0; kb < KB; ++kb)
#pragma unroll
      for (int f = 0; f < NF; ++f)
        acc[f] = __builtin_amdgcn_mfma_f32_16x16x32_bf16(a_cur[kb], b[kb][f],
                                                         acc[f], 0, 0, 0);
#pragma unroll
    for (int f = 0; f < NF; ++f) {
      const int col = colbase + f * 16 + lc;
#pragma unroll
      for (int i = 0; i < 4; ++i) {
        const int row = bm + t * 16 + khi * 4 + i;
        float v = acc[f][i] + bias_f[f];
        if (ACT && v < 0.f) v *= sl;
        if (CBF) ((unsigned short*)s.C)[(size_t)row * ldc + col] = f2bf(v);
        else     ((float*)s.C)[(size_t)row * ldc + col] = v;
      }
    }
#pragma unroll
    for (int kb = 0; kb < KB; ++kb) a_cur[kb] = a_nxt[kb];
  }
}

extern "C" void kernel_launch(void* const* d_in, const int* in_sizes, int n_in,
                              void* d_out, int out_size, void* d_ws, size_t ws_size,
                              hipStream_t stream) {
  const float* features_v = (const float*)d_in[0];
  const float* features_u = (const float*)d_in[1];
  const int* edge_v = (const int*)d_in[2];
  const int* edge_u = (const int*)d_in[3];
  const float* Wv1 = (const float*)d_in[4];
  const float* bv1 = (const float*)d_in[5];
  const float* av1 = (const float*)d_in[6];
  const float* Wu1 = (const float*)d_in[7];
  const float* bu1 = (const float*)d_in[8];
  const float* au1 = (const float*)d_in[9];
  const float* Wv2 = (const float*)d_in[10];
  const float* bv2 = (const float*)d_in[11];
  const float* av2 = (const float*)d_in[12];
  const float* Wu2 = (const float*)d_in[13];
  const float* bu2 = (const float*)d_in[14];
  const float* au2 = (const float*)d_in[15];
  const float* Wv3 = (const float*)d_in[16];
  const float* bv3 = (const float*)d_in[17];
  const float* Wu3 = (const float*)d_in[18];
  const float* bu3 = (const float*)d_in[19];
  const int ne = in_sizes[2];

  // ---- workspace layout
  int* bcnt = (int*)d_ws;                        // [2*NB]
  int* bcur = bcnt + 2 * NB;                     // [2*NB] relative cursors
  int* off_v = bcur + 2 * NB;                    // [NV+1]
  int* off_u = off_v + NVN + 1;                  // [NU+1]
  unsigned short* csr_v = (unsigned short*)(off_u + NUN + 1);  // [ne]
  unsigned short* csr_u = csr_v + ne;                          // [ne]
  uintptr_t sbase = (((uintptr_t)(csr_u + ne)) + 15) & ~(uintptr_t)15;
  unsigned* stg_v = (unsigned*)sbase;            // [ne]
  unsigned* stg_u = stg_v + ne;                  // [ne]
  unsigned short* P1b = (unsigned short*)(stg_u + ne);  // [NV*128] bf16
  unsigned short* P2b = P1b + (size_t)NVN * 128; // [NU*128] bf16
  unsigned short* Ve3b = P2b + (size_t)NUN * 128;// [NV*128] bf16
  unsigned short* Ue3b = Ve3b + (size_t)NVN * 128;  // [NU*128] bf16
  unsigned short* Wb = Ue3b + (size_t)NUN * 128; // 6*32768 bf16
  unsigned short* Fbv = Wb + 6 * 32768;          // [NV*128] bf16 features_v
  unsigned short* Fbu = Fbv + (size_t)NVN * 128; // [NU*128] bf16 features_u

  float* out_v = (float*)d_out;              // [NV,256]
  float* out_u = out_v + (size_t)NVN * 256;  // [NU,256]

  const int hb = (ne + HCH - 1) / HCH;
  const dim3 gg((NVN * 64) / 256, 2);        // one wave per node, 2 sides
  const dim3 gr(NVN / (16 * TILES), 1, 2);   // 625 blocks, 2 sides
  const dim3 g12((NVN + 63) / 64, 1, 2);     // 782 blocks, 2 sides
  const dim3 gsc((ne + CH - 1) / CH, 2);
  const dim3 gbd(NB, 2);

  // ---- prep: weights -> bf16 Wt[N][K], features -> bf16, bucket histogram
  hipMemsetAsync(bcnt, 0, (size_t)(4 * NB) * 4, stream);
  PrepArgs pa;
  pa.w[0] = {Wv1, Wb + 0 * 32768, 128, 256};
  pa.w[1] = {Wu1, Wb + 1 * 32768, 128, 256};
  pa.w[2] = {Wv2, Wb + 2 * 32768, 256, 128};
  pa.w[3] = {Wu2, Wb + 3 * 32768, 256, 128};
  pa.w[4] = {Wv3, Wb + 4 * 32768, 256, 128};
  pa.w[5] = {Wu3, Wb + 5 * 32768, 256, 128};
  pa.fv = features_v; pa.fu = features_u;
  pa.fbv = Fbv; pa.fbu = Fbu;
  pa.ev = edge_v; pa.eu = edge_u;
  pa.bcnt = bcnt; pa.ne = ne;
  prep_kernel<<<768 + 6250 + hb, 256, 0, stream>>>(pa);
  bucket_scatter<<<gsc, 256, 0, stream>>>(edge_v, edge_u, bcnt, bcur,
                                          stg_v, stg_u, ne);
  bucket_build<<<gbd, 256, 0, stream>>>(off_v, off_u, bcnt, stg_v, stg_u,
                                        csr_v, csr_u, NVN, NUN);

  // ---- stage 1: neighbor means of bf16 features -> bf16
  {
    GSide a{(const unsigned*)Fbu, csr_v, off_v, nullptr, nullptr, nullptr, P1b, 64};
    GSide b{(const unsigned*)Fbv, csr_u, off_u, nullptr, nullptr, nullptr, P2b, 64};
    gatherk<0><<<gg, 256, 0, stream>>>(a, b, NVN);
  }
  // fused: Tv = prelu(P1b@Wv1+bv1)@Wu2 -> P1b ; Tu = prelu(P2b@Wu1+bu1)@Wv2 -> P2b
  {
    Gm12Side a{P1b, Wb + 0 * 32768, bv1, av1, Wb + 3 * 32768, P1b};
    Gm12Side b{P2b, Wb + 1 * 32768, bu1, au1, Wb + 2 * 32768, P2b};
    gemm12<<<g12, 256, 0, stream>>>(a, b, NVN);
  }
  // ---- stage 2: ve2 = prelu(mean_gather(Tu)+bv2) -> out_v[:,0:128]
  {
    GSide a{(const unsigned*)P2b, csr_v, off_v, bv2, av2, nullptr, out_v, 256};
    GSide b{(const unsigned*)P1b, csr_u, off_u, bu2, au2, nullptr, out_u, 256};
    gatherk<1><<<gg, 256, 0, stream>>>(a, b, NVN);
  }
  // ---- stage 3: ve3 = concat(ve2, fv)@Wv3+bv3 -> Ve3b (bf16)
  {
    GmSide a{out_v, Fbv, Wb + 4 * 32768, bv3, nullptr, Ve3b};
    GmSide b{out_u, Fbu, Wb + 5 * 32768, bu3, nullptr, Ue3b};
    gemm_reg<4, 4, 2, 0, 1, 1, 0><<<gr, 256, 0, stream>>>(a, b, 256, 128, 128, NVN);
  }
  // sv = (gather_sum(Ue3b)+Ve3b)/(deg_v+1) -> out_v[:,128:256]
  {
    GSide a{(const unsigned*)Ue3b, csr_v, off_v, nullptr, nullptr,
            (const unsigned*)Ve3b, out_v + 128, 256};
    GSide b{(const unsigned*)Ve3b, csr_u, off_u, nullptr, nullptr,
            (const unsigned*)Ue3b, out_u + 128, 256};
    gatherk<2><<<gg, 256, 0, stream>>>(a, b, NVN);
  }
}